// Round 2
// baseline (311.814 us; speedup 1.0000x reference)
//
#include <hip/hip_runtime.h>
#include <cstdint>
#include <cstddef>

#define BB 2048
#define LL 96
#define PP 96
#define NN 64
#define HSTRIDE 68   // u32 row stride for packed LDS tiles (64 + 4 pad, 16B-aligned)

typedef __attribute__((ext_vector_type(8))) short short8;  // 8 bf16 (4 VGPRs)
typedef __attribute__((ext_vector_type(4))) float f32x4;

union U4S8 { uint4 u; short8 s; };

__device__ __forceinline__ float siluf(float x) {
  return x * __builtin_amdgcn_rcpf(1.0f + __expf(-x));
}
__device__ __forceinline__ float tanhf_fast(float x) {
  return 1.0f - 2.0f * __builtin_amdgcn_rcpf(1.0f + __expf(2.0f * x));
}
__device__ __forceinline__ float rlane(float x, int l) {
  return __int_as_float(__builtin_amdgcn_readlane(__float_as_int(x), l));
}

// ---- DPP cross-lane ops (VALU pipe); HW-verified R7/R8 ----
template <int CTRL>
__device__ __forceinline__ float dppadd(float x) {
  int y = __builtin_amdgcn_update_dpp(0, __float_as_int(x), CTRL, 0xF, 0xF, false);
  return x + __int_as_float(y);
}
template <int CTRL>
__device__ __forceinline__ float dppmov(float x) {
  int y = __builtin_amdgcn_update_dpp(0, __float_as_int(x), CTRL, 0xF, 0xF, false);
  return __int_as_float(y);
}
// ds_swizzle XOR permutation (bit mode): offset = (xor<<10) | 0x1F
template <int IMM>
__device__ __forceinline__ float swzf(float x) {
  return __int_as_float(__builtin_amdgcn_ds_swizzle(__float_as_int(x), IMM));
}
__device__ __forceinline__ float wave_sum(float x) {
  x = dppadd<0xB1>(x);
  x = dppadd<0x4E>(x);
  x = dppadd<0x141>(x);
  x = dppadd<0x128>(x);
  x += __shfl_xor(x, 16, 64);
  x += __shfl_xor(x, 32, 64);
  return x;
}

// split fp32 -> (bf16 hi | bf16 lo) packed in one u32 (hi in top 16).
__device__ __forceinline__ uint32_t packsplit(float f) {
  uint32_t b = __float_as_uint(f);
  uint32_t h = b & 0xFFFF0000u;
  float r = f - __uint_as_float(h);
  return h | (__float_as_uint(r) >> 16);
}
__device__ __forceinline__ void splitpack2(float f0, float f1, uint32_t& dhi, uint32_t& dlo) {
  uint32_t b0 = __float_as_uint(f0), b1 = __float_as_uint(f1);
  uint32_t h0 = b0 & 0xFFFF0000u, h1 = b1 & 0xFFFF0000u;
  float r0 = f0 - __uint_as_float(h0), r1 = f1 - __uint_as_float(h1);
  dhi = (h0 >> 16) | h1;
  dlo = (__float_as_uint(r0) >> 16) | (__float_as_uint(r1) & 0xFFFF0000u);
}
__device__ __forceinline__ void unpack2(uint32_t p0, uint32_t p1, uint32_t& dhi, uint32_t& dlo) {
  dhi = (p0 >> 16) | (p1 & 0xFFFF0000u);
  dlo = (p0 & 0xFFFFu) | (p1 << 16);
}
__device__ __forceinline__ void readfrag(const uint32_t* p, short8& hi, short8& lo) {
  uint4 pa = *(const uint4*)p;
  uint4 pb = *(const uint4*)(p + 4);
  U4S8 h, l;
  unpack2(pa.x, pa.y, h.u.x, l.u.x);
  unpack2(pa.z, pa.w, h.u.y, l.u.y);
  unpack2(pb.x, pb.y, h.u.z, l.u.z);
  unpack2(pb.z, pb.w, h.u.w, l.u.w);
  hi = h.s; lo = l.s;
}
// 3-term split-bf16 product over 2 k-steps: acc += A*B (~fp32 accuracy)
__device__ __forceinline__ f32x4 mm_split(f32x4 acc, const short8* Ah, const short8* Al,
                                          const short8* Bh, const short8* Bl) {
  acc = __builtin_amdgcn_mfma_f32_16x16x32_bf16(Ah[0], Bh[0], acc, 0, 0, 0);
  acc = __builtin_amdgcn_mfma_f32_16x16x32_bf16(Ah[1], Bh[1], acc, 0, 0, 0);
  acc = __builtin_amdgcn_mfma_f32_16x16x32_bf16(Al[0], Bh[0], acc, 0, 0, 0);
  acc = __builtin_amdgcn_mfma_f32_16x16x32_bf16(Al[1], Bh[1], acc, 0, 0, 0);
  acc = __builtin_amdgcn_mfma_f32_16x16x32_bf16(Ah[0], Bl[0], acc, 0, 0, 0);
  acc = __builtin_amdgcn_mfma_f32_16x16x32_bf16(Ah[1], Bl[1], acc, 0, 0, 0);
  return acc;
}

// ---------------- K1: x_proj (R8 version: LDS dbuf weights) ------------------
__global__ __launch_bounds__(256, 2) void k_xproj(
    const float* __restrict__ x,
    const float* __restrict__ w0, const float* __restrict__ b0,
    const float* __restrict__ w1, const float* __restrict__ b1,
    const float* __restrict__ w2, const float* __restrict__ b2,
    const float* __restrict__ w3, const float* __restrict__ b3,
    const float* __restrict__ w4, const float* __restrict__ b4,
    float* __restrict__ x_old, float* __restrict__ out)
{
  __shared__ uint32_t hbuf[128 * HSTRIDE];
  __shared__ uint32_t wbufA[64 * HSTRIDE];
  __shared__ uint32_t wbufB[64 * HSTRIDE];
  __shared__ float bs[320];

  int tid = threadIdx.x;
  int wave = tid >> 6, lane = tid & 63;
  int quad = lane >> 4, m16 = lane & 15;
  size_t tokBase = (size_t)blockIdx.x * 128;

  {
    size_t e = tokBase * 8 + (size_t)tid * 4;
    *(float4*)(out + e) = *(const float4*)(x + e);
  }
  if (tid < 64) {
    bs[tid]       = b0[tid];
    bs[64 + tid]  = b1[tid];
    bs[128 + tid] = b2[tid];
    bs[192 + tid] = b3[tid];
    bs[256 + tid] = b4[tid];
  }
  #pragma unroll
  for (int i = 0; i < 4; ++i) {
    int e4 = i * 256 + tid;
    int o = e4 >> 4, k = (e4 & 15) << 2;
    float4 wv = ((const float4*)w1)[e4];
    *(uint4*)(wbufA + o * HSTRIDE + k) =
        make_uint4(packsplit(wv.x), packsplit(wv.y), packsplit(wv.z), packsplit(wv.w));
  }
  __syncthreads();

  short8 A0h[2], A0l[2];
  #pragma unroll
  for (int mt = 0; mt < 2; ++mt) {
    U4S8 h, l;
    h.u = make_uint4(0, 0, 0, 0); l.u = make_uint4(0, 0, 0, 0);
    if (quad == 0) {
      const float* xp = x + (tokBase + wave * 32 + mt * 16 + m16) * 8;
      float4 xa = *(const float4*)xp;
      float4 xb = *(const float4*)(xp + 4);
      splitpack2(xa.x, xa.y, h.u.x, l.u.x);
      splitpack2(xa.z, xa.w, h.u.y, l.u.y);
      splitpack2(xb.x, xb.y, h.u.z, l.u.z);
      splitpack2(xb.z, xb.w, h.u.w, l.u.w);
    }
    A0h[mt] = h.s; A0l[mt] = l.s;
  }
  short8 B0h[4], B0l[4];
  #pragma unroll
  for (int nt = 0; nt < 4; ++nt) {
    U4S8 h, l;
    h.u = make_uint4(0, 0, 0, 0); l.u = make_uint4(0, 0, 0, 0);
    if (quad == 0) {
      const float* wp = w0 + (nt * 16 + m16) * 8;
      float4 wa = *(const float4*)wp;
      float4 wb = *(const float4*)(wp + 4);
      splitpack2(wa.x, wa.y, h.u.x, l.u.x);
      splitpack2(wa.z, wa.w, h.u.y, l.u.y);
      splitpack2(wb.x, wb.y, h.u.z, l.u.z);
      splitpack2(wb.z, wb.w, h.u.w, l.u.w);
    }
    B0h[nt] = h.s; B0l[nt] = l.s;
  }
  {
    f32x4 acc[2][4];
    #pragma unroll
    for (int mt = 0; mt < 2; ++mt)
      #pragma unroll
      for (int nt = 0; nt < 4; ++nt) {
        float bv = bs[nt * 16 + m16];
        acc[mt][nt] = (f32x4){bv, bv, bv, bv};
      }
    #pragma unroll
    for (int mt = 0; mt < 2; ++mt)
      #pragma unroll
      for (int nt = 0; nt < 4; ++nt)
        acc[mt][nt] = __builtin_amdgcn_mfma_f32_16x16x32_bf16(A0h[mt], B0h[nt], acc[mt][nt], 0, 0, 0);
    #pragma unroll
    for (int mt = 0; mt < 2; ++mt)
      #pragma unroll
      for (int nt = 0; nt < 4; ++nt)
        acc[mt][nt] = __builtin_amdgcn_mfma_f32_16x16x32_bf16(A0l[mt], B0h[nt], acc[mt][nt], 0, 0, 0);
    #pragma unroll
    for (int mt = 0; mt < 2; ++mt)
      #pragma unroll
      for (int nt = 0; nt < 4; ++nt)
        acc[mt][nt] = __builtin_amdgcn_mfma_f32_16x16x32_bf16(A0h[mt], B0l[nt], acc[mt][nt], 0, 0, 0);
    #pragma unroll
    for (int mt = 0; mt < 2; ++mt)
      #pragma unroll
      for (int nt = 0; nt < 4; ++nt)
        #pragma unroll
        for (int r = 0; r < 4; ++r) {
          float s = siluf(acc[mt][nt][r]);
          hbuf[(wave * 32 + mt * 16 + quad * 4 + r) * HSTRIDE + nt * 16 + m16] = packsplit(s);
        }
  }

  const float* Ws[4] = {w1, w2, w3, w4};
  uint32_t* cur = wbufA;
  uint32_t* nxt = wbufB;
  #pragma unroll 1
  for (int lyr = 0; lyr < 4; ++lyr) {
    float4 wv[4];
    if (lyr < 3) {
      const float* wn = Ws[lyr + 1];
      #pragma unroll
      for (int i = 0; i < 4; ++i) wv[i] = ((const float4*)wn)[i * 256 + tid];
    }
    short8 Bh[8], Bl[8];
    #pragma unroll
    for (int nt = 0; nt < 4; ++nt)
      #pragma unroll
      for (int ks = 0; ks < 2; ++ks)
        readfrag(cur + (nt * 16 + m16) * HSTRIDE + ks * 32 + quad * 8, Bh[nt * 2 + ks], Bl[nt * 2 + ks]);
    short8 Ah[4], Al[4];
    #pragma unroll
    for (int mt = 0; mt < 2; ++mt)
      #pragma unroll
      for (int ks = 0; ks < 2; ++ks)
        readfrag(hbuf + (wave * 32 + mt * 16 + m16) * HSTRIDE + ks * 32 + quad * 8, Ah[mt * 2 + ks], Al[mt * 2 + ks]);

    f32x4 acc[2][4];
    #pragma unroll
    for (int mt = 0; mt < 2; ++mt)
      #pragma unroll
      for (int nt = 0; nt < 4; ++nt) {
        float bv = bs[(lyr + 1) * 64 + nt * 16 + m16];
        acc[mt][nt] = (f32x4){bv, bv, bv, bv};
      }
    #pragma unroll
    for (int ks = 0; ks < 2; ++ks)
      #pragma unroll
      for (int mt = 0; mt < 2; ++mt)
        #pragma unroll
        for (int nt = 0; nt < 4; ++nt)
          acc[mt][nt] = __builtin_amdgcn_mfma_f32_16x16x32_bf16(Ah[mt * 2 + ks], Bh[nt * 2 + ks], acc[mt][nt], 0, 0, 0);
    #pragma unroll
    for (int ks = 0; ks < 2; ++ks)
      #pragma unroll
      for (int mt = 0; mt < 2; ++mt)
        #pragma unroll
        for (int nt = 0; nt < 4; ++nt)
          acc[mt][nt] = __builtin_amdgcn_mfma_f32_16x16x32_bf16(Al[mt * 2 + ks], Bh[nt * 2 + ks], acc[mt][nt], 0, 0, 0);
    #pragma unroll
    for (int ks = 0; ks < 2; ++ks)
      #pragma unroll
      for (int mt = 0; mt < 2; ++mt)
        #pragma unroll
        for (int nt = 0; nt < 4; ++nt)
          acc[mt][nt] = __builtin_amdgcn_mfma_f32_16x16x32_bf16(Ah[mt * 2 + ks], Bl[nt * 2 + ks], acc[mt][nt], 0, 0, 0);

    if (lyr < 3) {
      #pragma unroll
      for (int i = 0; i < 4; ++i) {
        int e4 = i * 256 + tid;
        int o = e4 >> 4, k = (e4 & 15) << 2;
        *(uint4*)(nxt + o * HSTRIDE + k) =
            make_uint4(packsplit(wv[i].x), packsplit(wv[i].y), packsplit(wv[i].z), packsplit(wv[i].w));
      }
    }

    if (lyr < 3) {
      #pragma unroll
      for (int mt = 0; mt < 2; ++mt)
        #pragma unroll
        for (int nt = 0; nt < 4; ++nt)
          #pragma unroll
          for (int r = 0; r < 4; ++r) {
            float s = siluf(acc[mt][nt][r]);
            hbuf[(wave * 32 + mt * 16 + quad * 4 + r) * HSTRIDE + nt * 16 + m16] = packsplit(s);
          }
    } else {
      #pragma unroll
      for (int mt = 0; mt < 2; ++mt)
        #pragma unroll
        for (int nt = 0; nt < 4; ++nt)
          #pragma unroll
          for (int r = 0; r < 4; ++r) {
            size_t t = tokBase + wave * 32 + mt * 16 + quad * 4 + r;
            x_old[t * 64 + nt * 16 + m16] = acc[mt][nt][r];
          }
    }
    __syncthreads();
    uint32_t* tmp = cur; cur = nxt; nxt = tmp;
  }
}

// ------- K2: per-batch conv + compression + v + z0 (R8 version) -------------
__global__ __launch_bounds__(256) void k_hist(
    const float* __restrict__ x_old,
    const float* __restrict__ conv_w, const float* __restrict__ conv_b,
    const float* __restrict__ comp_w, const float* __restrict__ comp_b,
    const float* __restrict__ xw0, const float* __restrict__ xb0,
    const float* __restrict__ xw1, const float* __restrict__ xb1,
    float* __restrict__ a0_o, float* __restrict__ v_o, float* __restrict__ z0_o)
{
  __shared__ float xo[LL * NN];
  __shared__ float red[32];
  __shared__ float hbuf[64];
  int b = blockIdx.x, tid = threadIdx.x;
  const float* src = x_old + (size_t)b * (LL * NN);
  #pragma unroll
  for (int i = 0; i < 6; ++i) {
    int e = (i * 256 + tid) * 4;
    *(float4*)(xo + e) = *(const float4*)(src + e);
  }
  __syncthreads();
  int c = tid & 63;
  float cw0 = conv_w[c * 3], cw1 = conv_w[c * 3 + 1], cw2 = conv_w[c * 3 + 2];
  float cb = conv_b[c];
  float acc[8];
  #pragma unroll
  for (int q = 0; q < 8; ++q) acc[q] = 0.f;
  #pragma unroll 1
  for (int j = 0; j < 24; ++j) {
    int e = j * 256 + tid;
    int t = e >> 6;
    float s = xo[t * 64 + c] * cw0 + cb;
    if (t + 2 < LL) s += xo[(t + 2) * 64 + c] * cw1;
    if (t + 4 < LL) s += xo[(t + 4) * 64 + c] * cw2;
    float hv = siluf(s);
    #pragma unroll
    for (int q = 0; q < 8; ++q) acc[q] += hv * comp_w[q * 6144 + e];
  }
  #pragma unroll
  for (int q = 0; q < 8; ++q) acc[q] = dppadd<0xB1>(acc[q]);
  #pragma unroll
  for (int q = 0; q < 8; ++q) acc[q] = dppadd<0x4E>(acc[q]);
  #pragma unroll
  for (int q = 0; q < 8; ++q) acc[q] = dppadd<0x141>(acc[q]);
  #pragma unroll
  for (int q = 0; q < 8; ++q) acc[q] = dppadd<0x128>(acc[q]);
  #pragma unroll
  for (int q = 0; q < 8; ++q) acc[q] += __shfl_xor(acc[q], 16, 64);
  #pragma unroll
  for (int q = 0; q < 8; ++q) acc[q] += __shfl_xor(acc[q], 32, 64);
  int wave = tid >> 6, lane = tid & 63;
  if (lane < 8) {
    float sel = acc[0];
    #pragma unroll
    for (int q = 1; q < 8; ++q) sel = (lane == q) ? acc[q] : sel;
    red[wave * 8 + lane] = sel;
  }
  __syncthreads();
  if (tid < 8)
    a0_o[b * 8 + tid] = red[tid] + red[8 + tid] + red[16 + tid] + red[24 + tid] + comp_b[tid];
  if (tid < 64) {
    float a2 = xb0[tid];
    #pragma unroll 8
    for (int k = 0; k < 64; ++k) a2 += xw0[tid * 64 + k] * xo[6080 + k];
    hbuf[tid] = siluf(a2);
  }
  __syncthreads();
  float vr = 0.f;
  if (tid < 64) {
    vr = xb1[tid];
    #pragma unroll 8
    for (int k = 0; k < 64; ++k) vr += xw1[tid * 64 + k] * hbuf[k];
  }
  float s2 = wave_sum(vr * vr);
  if (tid < 64) {
    float nrm = sqrtf(s2) + 1e-8f;
    v_o[b * 64 + tid] = vr / nrm;
    z0_o[b * 64 + tid] = xo[6080 + tid];
  }
}

// ------------- K3: 96-step ODE scan (R10) -----------------------------------
// R8 = 1 batch/wave, 2 waves/SIMD, LDS round-trip for the W1.h octet gather:
// 59.3 us, chain ~1480 cyc/step. R9 (2 batch/wave, 1 wave/SIMD) REGRESSED to
// 64.7 us (VALUBusy 53->42): single wave can't hide LDS/shuffle latency.
// R10: back to 1 batch/wave; replace the hs LDS write->read round-trip
// (~200+ cyc on the serial chain) with an in-register octet all-gather:
// xor1/2/3/7 via DPP (VALU pipe), xor4/5/6 via 3 parallel ds_swizzle.
// Weights are pre-permuted at init so the dot stays exact:
//   wx[m] = nw1[i8*64 + oct*8 + (i8^m)]  pairs with  h from lane (lane^m).
// Dot chains tree-reduced (depth 8 -> 3).
__global__ __launch_bounds__(256) void k_scan(
    const float* __restrict__ a0_i, const float* __restrict__ v_i, const float* __restrict__ z0_i,
    const float* __restrict__ nw0, const float* __restrict__ nb0_p,
    const float* __restrict__ nw1, const float* __restrict__ nb1_p,
    const float* __restrict__ lw0, const float* __restrict__ lb0_p,
    const float* __restrict__ lw1, const float* __restrict__ lb1_p,
    const float* __restrict__ spanA, float* __restrict__ atraj, uint32_t* __restrict__ ztraj)
{
  int tid = threadIdx.x;
  int lane = tid & 63;
  int wv = tid >> 6;
  int b = blockIdx.x * 4 + wv;
  float dt = fminf(fmaxf(spanA[0], 1e-8f), 7.0f);
  int i8 = lane & 7;
  int oct = lane >> 3;

  float w0r[8], wx[8], g0r[8], d1r[8];
  #pragma unroll
  for (int i = 0; i < 8; ++i) w0r[i] = nw0[lane * 8 + i];
  #pragma unroll
  for (int m = 0; m < 8; ++m) wx[m] = nw1[i8 * 64 + oct * 8 + (i8 ^ m)];
  #pragma unroll
  for (int i = 0; i < 8; ++i) g0r[i] = lw0[i8 * 8 + i];
  #pragma unroll
  for (int i = 0; i < 8; ++i) d1r[i] = lw1[lane * 8 + i];
  float nb0 = nb0_p[lane];
  float nb1o = nb1_p[i8];
  float lb0o = lb0_p[i8];
  float lb1 = lb1_p[lane];
  float v = v_i[b * 64 + lane];
  float z = z0_i[b * 64 + lane];
  float a_own = a0_i[b * 8 + i8];
  float t0 = wave_sum(v * z);
  float w = z - 2.0f * t0 * v;
  float a_s[8];
  #pragma unroll
  for (int i = 0; i < 8; ++i) a_s[i] = rlane(a_own, i);

  float* ab = atraj + (size_t)b * (PP * 8);
  uint32_t* zb = ztraj + (size_t)b * (PP * NN);
  #pragma unroll 1
  for (int p = 0; p < PP; ++p) {
    // ---- h = silu(nb0 + W0 a): tree-reduced dot ----
    float u0 = w0r[0] * a_s[0] + w0r[1] * a_s[1];
    float u1 = w0r[2] * a_s[2] + w0r[3] * a_s[3];
    float u2 = w0r[4] * a_s[4] + w0r[5] * a_s[5];
    float u3 = w0r[6] * a_s[6] + w0r[7] * a_s[7];
    float h = siluf(nb0 + ((u0 + u1) + (u2 + u3)));
    // ---- octet all-gather of h, in-register (no LDS round-trip) ----
    float v1 = dppmov<0xB1>(h);    // h ^ 1
    float v2 = dppmov<0x4E>(h);    // h ^ 2
    float v3 = dppmov<0x1B>(h);    // h ^ 3
    float v7 = dppmov<0x141>(h);   // h ^ 7 (row_half_mirror)
    float v4 = swzf<0x101F>(h);    // h ^ 4
    float v5 = swzf<0x101F>(v1);   // h ^ 5
    float v6 = swzf<0x101F>(v2);   // h ^ 6
    float q0 = wx[0] * h  + wx[1] * v1;
    float q1 = wx[2] * v2 + wx[3] * v3;
    float q2 = wx[4] * v4 + wx[5] * v5;
    float q3 = wx[6] * v6 + wx[7] * v7;
    float ps = (q0 + q1) + (q2 + q3);
    // ---- cross-octet reduce ----
    ps += swzf<0x201F>(ps);        // ^ 8
    ps += swzf<0x401F>(ps);        // ^ 16
    ps += __shfl_xor(ps, 32, 64);  // ^ 32
    float da_own = tanhf_fast(ps + nb1o);
    // ---- d chain (independent of h chain) ----
    float e0 = g0r[0] * a_s[0] + g0r[1] * a_s[1];
    float e1 = g0r[2] * a_s[2] + g0r[3] * a_s[3];
    float e2 = g0r[4] * a_s[4] + g0r[5] * a_s[5];
    float e3 = g0r[6] * a_s[6] + g0r[7] * a_s[7];
    float g_own = siluf(lb0o + ((e0 + e1) + (e2 + e3)));
    float f0 = d1r[0] * rlane(g_own, 0) + d1r[1] * rlane(g_own, 1);
    float f1 = d1r[2] * rlane(g_own, 2) + d1r[3] * rlane(g_own, 3);
    float f2 = d1r[4] * rlane(g_own, 4) + d1r[5] * rlane(g_own, 5);
    float f3 = d1r[6] * rlane(g_own, 6) + d1r[7] * rlane(g_own, 7);
    float d = lb1 + ((f0 + f1) + (f2 + f3));
    // ---- state update ----
    a_own += dt * da_own;
    #pragma unroll
    for (int i = 0; i < 8; ++i) a_s[i] = rlane(a_own, i);
    w *= (1.0f + dt * d);
    float t1 = wave_sum(v * w);
    float zv = w - 2.0f * t1 * v;
    if (lane < 8) ab[p * 8 + lane] = a_own;
    zb[p * 64 + lane] = packsplit(zv);
  }
}

// --------- K4: post nets, register-resident M + ebuf-aliases-wbuf -----------
// LDS = wbuf only (39.7 KB) -> 4 blocks/CU. Pass-1 results stay in registers
// (C-layout); combine via DPP half-row reduce + ror8 partner pull.
__global__ __launch_bounds__(256, 4) void k_post(
    const float* __restrict__ atraj, const uint32_t* __restrict__ ztraj,
    const float* __restrict__ cw0, const float* __restrict__ cb0,
    const float* __restrict__ cw1, const float* __restrict__ cb1,
    const float* __restrict__ zw0, const float* __restrict__ zb0,
    const float* __restrict__ zw1, const float* __restrict__ zb1,
    float* __restrict__ out)
{
  __shared__ uint32_t wbuf[144 * HSTRIDE];  // 39168 B; rows 0..63 reused as ebuf
  __shared__ float    cw0s[64];
  __shared__ float    cb0s[8];
  __shared__ float    zb0s[64];
  __shared__ float    zb1s[8];

  int tid = threadIdx.x;
  int wave = tid >> 6, lane = tid & 63;
  int quad = lane >> 4, m16 = lane & 15;
  size_t tokBase = (size_t)blockIdx.x * 64;

  // ---- stage all weights once (144 rows x 64) ----
  #pragma unroll
  for (int i = 0; i < 36; ++i) {
    int e = i * 256 + tid;
    int o = e >> 6, k = e & 63;
    float wv;
    if (o < 64)       wv = cw1[(((o >> 3) * 64 + k) << 3) + (o & 7)];
    else if (o < 72)  wv = cb1[(o - 64) * 64 + k];
    else if (o < 136) wv = zw0[(o - 72) * 64 + k];
    else              wv = zw1[(o - 136) * 64 + k];
    wbuf[o * HSTRIDE + k] = packsplit(wv);
  }
  if (tid < 64) cw0s[tid] = cw0[tid];
  if (tid < 8)  cb0s[tid] = cb0[tid];
  if (tid < 64) zb0s[tid] = zb0[tid];
  if (tid < 8)  zb1s[tid] = zb1[tid];
  __syncthreads();

  // ---- A-frags (Z) from global packed ztraj ----
  const uint32_t* zp = ztraj + (tokBase + wave * 16 + m16) * 64;
  short8 Ah[2], Al[2];
  readfrag(zp + quad * 8,      Ah[0], Al[0]);
  readfrag(zp + 32 + quad * 8, Ah[1], Al[1]);

  // ---- pass 1: M (nt 0..3) + ybias (nt 4) -> registers ----
  f32x4 acc1[5];
  #pragma unroll
  for (int nt = 0; nt < 5; ++nt) {
    short8 Bh[2], Bl[2];
    readfrag(wbuf + (nt * 16 + m16) * HSTRIDE + quad * 8,      Bh[0], Bl[0]);
    readfrag(wbuf + (nt * 16 + m16) * HSTRIDE + 32 + quad * 8, Bh[1], Bl[1]);
    f32x4 acc = (f32x4){0.f, 0.f, 0.f, 0.f};
    acc1[nt] = mm_split(acc, Ah, Al, Bh, Bl);
  }
  __syncthreads();  // all pass-1 reads of rows 0..79 done -> rows 0..63 reusable

  // ---- pass 2: E = silu(Z @ zw0^T + zb0) -> ebuf (= wbuf rows 0..63) ----
  uint32_t* ebuf = wbuf;
  #pragma unroll
  for (int nt = 0; nt < 4; ++nt) {
    short8 Bh[2], Bl[2];
    readfrag(wbuf + (72 + nt * 16 + m16) * HSTRIDE + quad * 8,      Bh[0], Bl[0]);
    readfrag(wbuf + (72 + nt * 16 + m16) * HSTRIDE + 32 + quad * 8, Bh[1], Bl[1]);
    f32x4 acc = (f32x4){0.f, 0.f, 0.f, 0.f};
    acc = mm_split(acc, Ah, Al, Bh, Bl);
    int m = nt * 16 + m16;
    float zbv = zb0s[m];
    #pragma unroll
    for (int r = 0; r < 4; ++r) {
      float e = siluf(acc[r] + zbv);
      ebuf[(wave * 16 + quad * 4 + r) * HSTRIDE + m] = packsplit(e);
    }
  }

  // ---- pass 3: add = E @ zw1^T + zb1 (ebuf rows wave-private, in-order) ----
  f32x4 acc3;
  {
    short8 Eh[2], El[2];
    readfrag(ebuf + (wave * 16 + m16) * HSTRIDE + quad * 8,      Eh[0], El[0]);
    readfrag(ebuf + (wave * 16 + m16) * HSTRIDE + 32 + quad * 8, Eh[1], El[1]);
    short8 Bh[2], Bl[2];
    int brow = 136 + (m16 & 7);   // duplicate rows for m16>=8; results unused there
    readfrag(wbuf + brow * HSTRIDE + quad * 8,      Bh[0], Bl[0]);
    readfrag(wbuf + brow * HSTRIDE + 32 + quad * 8, Bh[1], Bl[1]);
    f32x4 acc = (f32x4){0.f, 0.f, 0.f, 0.f};
    acc3 = mm_split(acc, Eh, El, Bh, Bl);
  }

  // ---- in-register combine ----
  // Lane (quad, m16) holds M[t=q*4+r][o=nt*16+m16]; c=nt*2+(m16>>3), j=m16&7.
  // yc[t][c] = sum_j g2[t][j] * M[t][c*8+j]: 8-lane half-row reduce; ror8
  // pulls the other half's c-parity. ybias = acc1[4], add = acc3 (lane c=m16<8).
  int j = m16 & 7;
  float cwj[8];
  #pragma unroll
  for (int i = 0; i < 8; ++i) cwj[i] = cw0s[j * 8 + i];
  float cbj = cb0s[j];
  #pragma unroll
  for (int r = 0; r < 4; ++r) {
    size_t idx = tokBase + wave * 16 + quad * 4 + r;
    const float* ap = atraj + idx * 8;
    float4 a0v = *(const float4*)ap;
    float4 a1v = *(const float4*)(ap + 4);
    float g2v = cbj
      + cwj[0] * a0v.x + cwj[1] * a0v.y + cwj[2] * a0v.z + cwj[3] * a0v.w
      + cwj[4] * a1v.x + cwj[5] * a1v.y + cwj[6] * a1v.z + cwj[7] * a1v.w;
    g2v = siluf(g2v);
    float yc[4], qo[4];
    #pragma unroll
    for (int nt = 0; nt < 4; ++nt) {
      float p = acc1[nt][r] * g2v;
      p = dppadd<0xB1>(p);
      p = dppadd<0x4E>(p);
      p = dppadd<0x141>(p);     // sum over 8-lane half-row
      yc[nt] = p;               // c = nt*2 + (m16>>3)
      qo[nt] = dppmov<0x128>(p);// partner half's value: c = nt*2 + 1-(m16>>3)
    }
    if (m16 < 8) {
      int cc = m16;
      int nt = cc >> 1;
      float ye = (nt == 0) ? yc[0] : (nt == 1) ? yc[1] : (nt == 2) ? yc[2] : yc[3];
      float yo = (nt == 0) ? qo[0] : (nt == 1) ? qo[1] : (nt == 2) ? qo[2] : qo[3];
      float y = (cc & 1) ? yo : ye;
      y += acc1[4][r] + acc3[r] + zb1s[cc];
      out[(size_t)(BB * LL * 8) + idx * 8 + cc] = y;
    }
  }
}

extern "C" void kernel_launch(void* const* d_in, const int* in_sizes, int n_in,
                              void* d_out, int out_size, void* d_ws, size_t ws_size,
                              hipStream_t stream) {
  const float* x      = (const float*)d_in[0];
  const float* xp_w0  = (const float*)d_in[1];
  const float* xp_b0  = (const float*)d_in[2];
  const float* xp_w1  = (const float*)d_in[3];
  const float* xp_b1  = (const float*)d_in[4];
  const float* xp_w2  = (const float*)d_in[5];
  const float* xp_b2  = (const float*)d_in[6];
  const float* xp_w3  = (const float*)d_in[7];
  const float* xp_b3  = (const float*)d_in[8];
  const float* xp_w4  = (const float*)d_in[9];
  const float* xp_b4  = (const float*)d_in[10];
  const float* xpp_w0 = (const float*)d_in[11];
  const float* xpp_b0 = (const float*)d_in[12];
  const float* xpp_w1 = (const float*)d_in[13];
  const float* xpp_b1 = (const float*)d_in[14];
  const float* conv_w = (const float*)d_in[15];
  const float* conv_b = (const float*)d_in[16];
  const float* span_A = (const float*)d_in[17];
  const float* comp_w = (const float*)d_in[18];
  const float* comp_b = (const float*)d_in[19];
  const float* net_w0 = (const float*)d_in[20];
  const float* net_b0 = (const float*)d_in[21];
  const float* net_w1 = (const float*)d_in[22];
  const float* net_b1 = (const float*)d_in[23];
  const float* lo_w0  = (const float*)d_in[24];
  const float* lo_b0  = (const float*)d_in[25];
  const float* lo_w1  = (const float*)d_in[26];
  const float* lo_b1  = (const float*)d_in[27];
  const float* lc_w0  = (const float*)d_in[28];
  const float* lc_b0  = (const float*)d_in[29];
  const float* lc_w1  = (const float*)d_in[30];
  const float* lc_b1  = (const float*)d_in[31];
  const float* lz_w0  = (const float*)d_in[32];
  const float* lz_b0  = (const float*)d_in[33];
  const float* lz_w1  = (const float*)d_in[34];
  const float* lz_b1  = (const float*)d_in[35];

  float*    ws    = (float*)d_ws;
  float*    x_old = ws;                    // (B,L,64) fp32
  uint32_t* ztraj = (uint32_t*)ws;         // (B,P,64) packed u32 — aliases x_old
  float*    atraj = ws + 12582912;         // (B,P,8)
  float*    a0    = ws + 14155776;         // (B,8)
  float*    vv    = a0 + 2048 * 8;         // (B,64)
  float*    z0    = vv + 2048 * 64;        // (B,64)
  float*    out   = (float*)d_out;

  hipLaunchKernelGGL(k_xproj, dim3(1536), dim3(256), 0, stream,
                     x, xp_w0, xp_b0, xp_w1, xp_b1, xp_w2, xp_b2, xp_w3, xp_b3,
                     xp_w4, xp_b4, x_old, out);
  hipLaunchKernelGGL(k_hist, dim3(2048), dim3(256), 0, stream,
                     x_old, conv_w, conv_b, comp_w, comp_b,
                     xpp_w0, xpp_b0, xpp_w1, xpp_b1, a0, vv, z0);
  hipLaunchKernelGGL(k_scan, dim3(512), dim3(256), 0, stream,
                     a0, vv, z0, net_w0, net_b0, net_w1, net_b1,
                     lo_w0, lo_b0, lo_w1, lo_b1, span_A, atraj, ztraj);
  hipLaunchKernelGGL(k_post, dim3(3072), dim3(256), 0, stream,
                     atraj, ztraj, lc_w0, lc_b0, lc_w1, lc_b1,
                     lz_w0, lz_b0, lz_w1, lz_b1, out);
}

// Round 3
// 303.688 us; speedup vs baseline: 1.0268x; 1.0268x over previous
//
#include <hip/hip_runtime.h>
#include <cstdint>
#include <cstddef>

#define BB 2048
#define LL 96
#define PP 96
#define NN 64
#define HSTRIDE 68   // u32 row stride for packed LDS tiles (64 + 4 pad, 16B-aligned)

typedef __attribute__((ext_vector_type(8))) short short8;  // 8 bf16 (4 VGPRs)
typedef __attribute__((ext_vector_type(4))) float f32x4;

union U4S8 { uint4 u; short8 s; };

__device__ __forceinline__ float siluf(float x) {
  return x * __builtin_amdgcn_rcpf(1.0f + __expf(-x));
}
__device__ __forceinline__ float tanhf_fast(float x) {
  return 1.0f - 2.0f * __builtin_amdgcn_rcpf(1.0f + __expf(2.0f * x));
}
__device__ __forceinline__ float rlane(float x, int l) {
  return __int_as_float(__builtin_amdgcn_readlane(__float_as_int(x), l));
}

// ---- DPP cross-lane ops (VALU pipe); HW-verified R7/R8 ----
template <int CTRL>
__device__ __forceinline__ float dppadd(float x) {
  int y = __builtin_amdgcn_update_dpp(0, __float_as_int(x), CTRL, 0xF, 0xF, false);
  return x + __int_as_float(y);
}
template <int CTRL>
__device__ __forceinline__ float dppmov(float x) {
  int y = __builtin_amdgcn_update_dpp(0, __float_as_int(x), CTRL, 0xF, 0xF, false);
  return __int_as_float(y);
}

// ---- permlane16/32_swap: VALU-pipe xor16/xor32 (gfx950). With both inputs
// equal to x, out0+out1 == x + x^{16,32} for EVERY lane (no select needed).
__device__ __forceinline__ float addswap16(float x) {
#if __has_builtin(__builtin_amdgcn_permlane16_swap)
  auto r = __builtin_amdgcn_permlane16_swap(__float_as_uint(x), __float_as_uint(x), false, false);
  return __uint_as_float(r[0]) + __uint_as_float(r[1]);
#else
  return x + __shfl_xor(x, 16, 64);
#endif
}
__device__ __forceinline__ float addswap32(float x) {
#if __has_builtin(__builtin_amdgcn_permlane32_swap)
  auto r = __builtin_amdgcn_permlane32_swap(__float_as_uint(x), __float_as_uint(x), false, false);
  return __uint_as_float(r[0]) + __uint_as_float(r[1]);
#else
  return x + __shfl_xor(x, 32, 64);
#endif
}
// value at lane^32 (hi = lane>=32): one permlane + cndmask, VALU pipe.
__device__ __forceinline__ float movswap32(float x, bool hi) {
#if __has_builtin(__builtin_amdgcn_permlane32_swap)
  auto r = __builtin_amdgcn_permlane32_swap(__float_as_uint(x), __float_as_uint(x), false, false);
  return __uint_as_float(hi ? r[0] : r[1]);
#else
  return __shfl_xor(x, 32, 64);
#endif
}

__device__ __forceinline__ float wave_sum(float x) {
  x = dppadd<0xB1>(x);    // ^1
  x = dppadd<0x4E>(x);    // ^2
  x = dppadd<0x141>(x);   // ^7 (row_half_mirror) -> octet sums
  x = dppadd<0x128>(x);   // ^8 (row_ror:8) -> 16-row sums
  x = addswap16(x);       // ^16 (VALU permlane)
  x = addswap32(x);       // ^32 (VALU permlane)
  return x;
}

// split fp32 -> (bf16 hi | bf16 lo) packed in one u32 (hi in top 16).
__device__ __forceinline__ uint32_t packsplit(float f) {
  uint32_t b = __float_as_uint(f);
  uint32_t h = b & 0xFFFF0000u;
  float r = f - __uint_as_float(h);
  return h | (__float_as_uint(r) >> 16);
}
__device__ __forceinline__ void splitpack2(float f0, float f1, uint32_t& dhi, uint32_t& dlo) {
  uint32_t b0 = __float_as_uint(f0), b1 = __float_as_uint(f1);
  uint32_t h0 = b0 & 0xFFFF0000u, h1 = b1 & 0xFFFF0000u;
  float r0 = f0 - __uint_as_float(h0), r1 = f1 - __uint_as_float(h1);
  dhi = (h0 >> 16) | h1;
  dlo = (__float_as_uint(r0) >> 16) | (__float_as_uint(r1) & 0xFFFF0000u);
}
__device__ __forceinline__ void unpack2(uint32_t p0, uint32_t p1, uint32_t& dhi, uint32_t& dlo) {
  dhi = (p0 >> 16) | (p1 & 0xFFFF0000u);
  dlo = (p0 & 0xFFFFu) | (p1 << 16);
}
__device__ __forceinline__ void readfrag(const uint32_t* p, short8& hi, short8& lo) {
  uint4 pa = *(const uint4*)p;
  uint4 pb = *(const uint4*)(p + 4);
  U4S8 h, l;
  unpack2(pa.x, pa.y, h.u.x, l.u.x);
  unpack2(pa.z, pa.w, h.u.y, l.u.y);
  unpack2(pb.x, pb.y, h.u.z, l.u.z);
  unpack2(pb.z, pb.w, h.u.w, l.u.w);
  hi = h.s; lo = l.s;
}
// 3-term split-bf16 product over 2 k-steps: acc += A*B (~fp32 accuracy)
__device__ __forceinline__ f32x4 mm_split(f32x4 acc, const short8* Ah, const short8* Al,
                                          const short8* Bh, const short8* Bl) {
  acc = __builtin_amdgcn_mfma_f32_16x16x32_bf16(Ah[0], Bh[0], acc, 0, 0, 0);
  acc = __builtin_amdgcn_mfma_f32_16x16x32_bf16(Ah[1], Bh[1], acc, 0, 0, 0);
  acc = __builtin_amdgcn_mfma_f32_16x16x32_bf16(Al[0], Bh[0], acc, 0, 0, 0);
  acc = __builtin_amdgcn_mfma_f32_16x16x32_bf16(Al[1], Bh[1], acc, 0, 0, 0);
  acc = __builtin_amdgcn_mfma_f32_16x16x32_bf16(Ah[0], Bl[0], acc, 0, 0, 0);
  acc = __builtin_amdgcn_mfma_f32_16x16x32_bf16(Ah[1], Bl[1], acc, 0, 0, 0);
  return acc;
}

// ---------------- K1: x_proj (R8 version: LDS dbuf weights) ------------------
__global__ __launch_bounds__(256, 2) void k_xproj(
    const float* __restrict__ x,
    const float* __restrict__ w0, const float* __restrict__ b0,
    const float* __restrict__ w1, const float* __restrict__ b1,
    const float* __restrict__ w2, const float* __restrict__ b2,
    const float* __restrict__ w3, const float* __restrict__ b3,
    const float* __restrict__ w4, const float* __restrict__ b4,
    float* __restrict__ x_old, float* __restrict__ out)
{
  __shared__ uint32_t hbuf[128 * HSTRIDE];
  __shared__ uint32_t wbufA[64 * HSTRIDE];
  __shared__ uint32_t wbufB[64 * HSTRIDE];
  __shared__ float bs[320];

  int tid = threadIdx.x;
  int wave = tid >> 6, lane = tid & 63;
  int quad = lane >> 4, m16 = lane & 15;
  size_t tokBase = (size_t)blockIdx.x * 128;

  {
    size_t e = tokBase * 8 + (size_t)tid * 4;
    *(float4*)(out + e) = *(const float4*)(x + e);
  }
  if (tid < 64) {
    bs[tid]       = b0[tid];
    bs[64 + tid]  = b1[tid];
    bs[128 + tid] = b2[tid];
    bs[192 + tid] = b3[tid];
    bs[256 + tid] = b4[tid];
  }
  #pragma unroll
  for (int i = 0; i < 4; ++i) {
    int e4 = i * 256 + tid;
    int o = e4 >> 4, k = (e4 & 15) << 2;
    float4 wv = ((const float4*)w1)[e4];
    *(uint4*)(wbufA + o * HSTRIDE + k) =
        make_uint4(packsplit(wv.x), packsplit(wv.y), packsplit(wv.z), packsplit(wv.w));
  }
  __syncthreads();

  short8 A0h[2], A0l[2];
  #pragma unroll
  for (int mt = 0; mt < 2; ++mt) {
    U4S8 h, l;
    h.u = make_uint4(0, 0, 0, 0); l.u = make_uint4(0, 0, 0, 0);
    if (quad == 0) {
      const float* xp = x + (tokBase + wave * 32 + mt * 16 + m16) * 8;
      float4 xa = *(const float4*)xp;
      float4 xb = *(const float4*)(xp + 4);
      splitpack2(xa.x, xa.y, h.u.x, l.u.x);
      splitpack2(xa.z, xa.w, h.u.y, l.u.y);
      splitpack2(xb.x, xb.y, h.u.z, l.u.z);
      splitpack2(xb.z, xb.w, h.u.w, l.u.w);
    }
    A0h[mt] = h.s; A0l[mt] = l.s;
  }
  short8 B0h[4], B0l[4];
  #pragma unroll
  for (int nt = 0; nt < 4; ++nt) {
    U4S8 h, l;
    h.u = make_uint4(0, 0, 0, 0); l.u = make_uint4(0, 0, 0, 0);
    if (quad == 0) {
      const float* wp = w0 + (nt * 16 + m16) * 8;
      float4 wa = *(const float4*)wp;
      float4 wb = *(const float4*)(wp + 4);
      splitpack2(wa.x, wa.y, h.u.x, l.u.x);
      splitpack2(wa.z, wa.w, h.u.y, l.u.y);
      splitpack2(wb.x, wb.y, h.u.z, l.u.z);
      splitpack2(wb.z, wb.w, h.u.w, l.u.w);
    }
    B0h[nt] = h.s; B0l[nt] = l.s;
  }
  {
    f32x4 acc[2][4];
    #pragma unroll
    for (int mt = 0; mt < 2; ++mt)
      #pragma unroll
      for (int nt = 0; nt < 4; ++nt) {
        float bv = bs[nt * 16 + m16];
        acc[mt][nt] = (f32x4){bv, bv, bv, bv};
      }
    #pragma unroll
    for (int mt = 0; mt < 2; ++mt)
      #pragma unroll
      for (int nt = 0; nt < 4; ++nt)
        acc[mt][nt] = __builtin_amdgcn_mfma_f32_16x16x32_bf16(A0h[mt], B0h[nt], acc[mt][nt], 0, 0, 0);
    #pragma unroll
    for (int mt = 0; mt < 2; ++mt)
      #pragma unroll
      for (int nt = 0; nt < 4; ++nt)
        acc[mt][nt] = __builtin_amdgcn_mfma_f32_16x16x32_bf16(A0l[mt], B0h[nt], acc[mt][nt], 0, 0, 0);
    #pragma unroll
    for (int mt = 0; mt < 2; ++mt)
      #pragma unroll
      for (int nt = 0; nt < 4; ++nt)
        acc[mt][nt] = __builtin_amdgcn_mfma_f32_16x16x32_bf16(A0h[mt], B0l[nt], acc[mt][nt], 0, 0, 0);
    #pragma unroll
    for (int mt = 0; mt < 2; ++mt)
      #pragma unroll
      for (int nt = 0; nt < 4; ++nt)
        #pragma unroll
        for (int r = 0; r < 4; ++r) {
          float s = siluf(acc[mt][nt][r]);
          hbuf[(wave * 32 + mt * 16 + quad * 4 + r) * HSTRIDE + nt * 16 + m16] = packsplit(s);
        }
  }

  const float* Ws[4] = {w1, w2, w3, w4};
  uint32_t* cur = wbufA;
  uint32_t* nxt = wbufB;
  #pragma unroll 1
  for (int lyr = 0; lyr < 4; ++lyr) {
    float4 wv[4];
    if (lyr < 3) {
      const float* wn = Ws[lyr + 1];
      #pragma unroll
      for (int i = 0; i < 4; ++i) wv[i] = ((const float4*)wn)[i * 256 + tid];
    }
    short8 Bh[8], Bl[8];
    #pragma unroll
    for (int nt = 0; nt < 4; ++nt)
      #pragma unroll
      for (int ks = 0; ks < 2; ++ks)
        readfrag(cur + (nt * 16 + m16) * HSTRIDE + ks * 32 + quad * 8, Bh[nt * 2 + ks], Bl[nt * 2 + ks]);
    short8 Ah[4], Al[4];
    #pragma unroll
    for (int mt = 0; mt < 2; ++mt)
      #pragma unroll
      for (int ks = 0; ks < 2; ++ks)
        readfrag(hbuf + (wave * 32 + mt * 16 + m16) * HSTRIDE + ks * 32 + quad * 8, Ah[mt * 2 + ks], Al[mt * 2 + ks]);

    f32x4 acc[2][4];
    #pragma unroll
    for (int mt = 0; mt < 2; ++mt)
      #pragma unroll
      for (int nt = 0; nt < 4; ++nt) {
        float bv = bs[(lyr + 1) * 64 + nt * 16 + m16];
        acc[mt][nt] = (f32x4){bv, bv, bv, bv};
      }
    #pragma unroll
    for (int ks = 0; ks < 2; ++ks)
      #pragma unroll
      for (int mt = 0; mt < 2; ++mt)
        #pragma unroll
        for (int nt = 0; nt < 4; ++nt)
          acc[mt][nt] = __builtin_amdgcn_mfma_f32_16x16x32_bf16(Ah[mt * 2 + ks], Bh[nt * 2 + ks], acc[mt][nt], 0, 0, 0);
    #pragma unroll
    for (int ks = 0; ks < 2; ++ks)
      #pragma unroll
      for (int mt = 0; mt < 2; ++mt)
        #pragma unroll
        for (int nt = 0; nt < 4; ++nt)
          acc[mt][nt] = __builtin_amdgcn_mfma_f32_16x16x32_bf16(Al[mt * 2 + ks], Bh[nt * 2 + ks], acc[mt][nt], 0, 0, 0);
    #pragma unroll
    for (int ks = 0; ks < 2; ++ks)
      #pragma unroll
      for (int mt = 0; mt < 2; ++mt)
        #pragma unroll
        for (int nt = 0; nt < 4; ++nt)
          acc[mt][nt] = __builtin_amdgcn_mfma_f32_16x16x32_bf16(Ah[mt * 2 + ks], Bl[nt * 2 + ks], acc[mt][nt], 0, 0, 0);

    if (lyr < 3) {
      #pragma unroll
      for (int i = 0; i < 4; ++i) {
        int e4 = i * 256 + tid;
        int o = e4 >> 4, k = (e4 & 15) << 2;
        *(uint4*)(nxt + o * HSTRIDE + k) =
            make_uint4(packsplit(wv[i].x), packsplit(wv[i].y), packsplit(wv[i].z), packsplit(wv[i].w));
      }
    }

    if (lyr < 3) {
      #pragma unroll
      for (int mt = 0; mt < 2; ++mt)
        #pragma unroll
        for (int nt = 0; nt < 4; ++nt)
          #pragma unroll
          for (int r = 0; r < 4; ++r) {
            float s = siluf(acc[mt][nt][r]);
            hbuf[(wave * 32 + mt * 16 + quad * 4 + r) * HSTRIDE + nt * 16 + m16] = packsplit(s);
          }
    } else {
      #pragma unroll
      for (int mt = 0; mt < 2; ++mt)
        #pragma unroll
        for (int nt = 0; nt < 4; ++nt)
          #pragma unroll
          for (int r = 0; r < 4; ++r) {
            size_t t = tokBase + wave * 32 + mt * 16 + quad * 4 + r;
            x_old[t * 64 + nt * 16 + m16] = acc[mt][nt][r];
          }
    }
    __syncthreads();
    uint32_t* tmp = cur; cur = nxt; nxt = tmp;
  }
}

// ------- K2: per-batch conv + compression + v + z0 (R8 version) -------------
__global__ __launch_bounds__(256) void k_hist(
    const float* __restrict__ x_old,
    const float* __restrict__ conv_w, const float* __restrict__ conv_b,
    const float* __restrict__ comp_w, const float* __restrict__ comp_b,
    const float* __restrict__ xw0, const float* __restrict__ xb0,
    const float* __restrict__ xw1, const float* __restrict__ xb1,
    float* __restrict__ a0_o, float* __restrict__ v_o, float* __restrict__ z0_o)
{
  __shared__ float xo[LL * NN];
  __shared__ float red[32];
  __shared__ float hbuf[64];
  int b = blockIdx.x, tid = threadIdx.x;
  const float* src = x_old + (size_t)b * (LL * NN);
  #pragma unroll
  for (int i = 0; i < 6; ++i) {
    int e = (i * 256 + tid) * 4;
    *(float4*)(xo + e) = *(const float4*)(src + e);
  }
  __syncthreads();
  int c = tid & 63;
  float cw0 = conv_w[c * 3], cw1 = conv_w[c * 3 + 1], cw2 = conv_w[c * 3 + 2];
  float cb = conv_b[c];
  float acc[8];
  #pragma unroll
  for (int q = 0; q < 8; ++q) acc[q] = 0.f;
  #pragma unroll 1
  for (int j = 0; j < 24; ++j) {
    int e = j * 256 + tid;
    int t = e >> 6;
    float s = xo[t * 64 + c] * cw0 + cb;
    if (t + 2 < LL) s += xo[(t + 2) * 64 + c] * cw1;
    if (t + 4 < LL) s += xo[(t + 4) * 64 + c] * cw2;
    float hv = siluf(s);
    #pragma unroll
    for (int q = 0; q < 8; ++q) acc[q] += hv * comp_w[q * 6144 + e];
  }
  #pragma unroll
  for (int q = 0; q < 8; ++q) acc[q] = dppadd<0xB1>(acc[q]);
  #pragma unroll
  for (int q = 0; q < 8; ++q) acc[q] = dppadd<0x4E>(acc[q]);
  #pragma unroll
  for (int q = 0; q < 8; ++q) acc[q] = dppadd<0x141>(acc[q]);
  #pragma unroll
  for (int q = 0; q < 8; ++q) acc[q] = dppadd<0x128>(acc[q]);
  #pragma unroll
  for (int q = 0; q < 8; ++q) acc[q] = addswap16(acc[q]);
  #pragma unroll
  for (int q = 0; q < 8; ++q) acc[q] = addswap32(acc[q]);
  int wave = tid >> 6, lane = tid & 63;
  if (lane < 8) {
    float sel = acc[0];
    #pragma unroll
    for (int q = 1; q < 8; ++q) sel = (lane == q) ? acc[q] : sel;
    red[wave * 8 + lane] = sel;
  }
  __syncthreads();
  if (tid < 8)
    a0_o[b * 8 + tid] = red[tid] + red[8 + tid] + red[16 + tid] + red[24 + tid] + comp_b[tid];
  if (tid < 64) {
    float a2 = xb0[tid];
    #pragma unroll 8
    for (int k = 0; k < 64; ++k) a2 += xw0[tid * 64 + k] * xo[6080 + k];
    hbuf[tid] = siluf(a2);
  }
  __syncthreads();
  float vr = 0.f;
  if (tid < 64) {
    vr = xb1[tid];
    #pragma unroll 8
    for (int k = 0; k < 64; ++k) vr += xw1[tid * 64 + k] * hbuf[k];
  }
  float s2 = wave_sum(vr * vr);
  if (tid < 64) {
    float nrm = sqrtf(s2) + 1e-8f;
    v_o[b * 64 + tid] = vr / nrm;
    z0_o[b * 64 + tid] = xo[6080 + tid];
  }
}

// ------------- K3: 96-step ODE scan (R11: all-VALU cross-lane) --------------
// R10 post-mortem: chain ~1500 cyc/step == ~6 dependent LDS-pipe cross-lane
// round-trips (ds_swizzle/ds_bpermute ~150 cyc each). R11 removes EVERY
// LDS-pipe op from the W1.h dot by relabeling the gather group:
//   group subspace  M = span{1,2,32}  (xor1/2/3 = DPP quad_perm; xor32 = one
//                                      permlane32_swap on the pre-permuted
//                                      high-half partial)
//   reduce subspace S = span{7,8,16}  (xor7 = DPP row_half_mirror, xor8 =
//                                      DPP row_ror:8, xor16 = permlane16_swap)
// Output-row label r(lane) = (l0^l1) | (l0^l2)<<1 | l5<<2 is constant on
// S-cosets; row i lives at lanes {0,2,4,6,32,34,36,38}[i]. wave_sum (t1) is
// likewise all-VALU. Output tail (t1/zv/stores) pipelined one step behind the
// recurrence so its chain overlaps the next step's issue.
__global__ __launch_bounds__(256) void k_scan(
    const float* __restrict__ a0_i, const float* __restrict__ v_i, const float* __restrict__ z0_i,
    const float* __restrict__ nw0, const float* __restrict__ nb0_p,
    const float* __restrict__ nw1, const float* __restrict__ nb1_p,
    const float* __restrict__ lw0, const float* __restrict__ lb0_p,
    const float* __restrict__ lw1, const float* __restrict__ lb1_p,
    const float* __restrict__ spanA, float* __restrict__ atraj, uint32_t* __restrict__ ztraj)
{
  int tid = threadIdx.x;
  int lane = tid & 63;
  int wv = tid >> 6;
  int b = blockIdx.x * 4 + wv;
  float dt = fminf(fmaxf(spanA[0], 1e-8f), 7.0f);
  int i8 = lane & 7;
  bool hi32 = lane >= 32;
  // output-row label, constant on span{7,8,16}-cosets
  int rrow = ((lane ^ (lane >> 1)) & 1) | (((lane ^ (lane >> 2)) & 1) << 1) | (((lane >> 5) & 1) << 2);

  float w0r[8], wxl[4], wxp[4], g0r[8], d1r[8];
  #pragma unroll
  for (int i = 0; i < 8; ++i) w0r[i] = nw0[lane * 8 + i];
  #pragma unroll
  for (int j = 0; j < 4; ++j) wxl[j] = nw1[rrow * 64 + (lane ^ j)];
  #pragma unroll
  for (int j = 0; j < 4; ++j) wxp[j] = nw1[(rrow ^ 4) * 64 + (lane ^ j)];
  #pragma unroll
  for (int i = 0; i < 8; ++i) g0r[i] = lw0[i8 * 8 + i];
  #pragma unroll
  for (int i = 0; i < 8; ++i) d1r[i] = lw1[lane * 8 + i];
  float nb0 = nb0_p[lane];
  float nb1r = nb1_p[rrow];
  float lb0o = lb0_p[i8];
  float lb1 = lb1_p[lane];
  float v = v_i[b * 64 + lane];
  float z = z0_i[b * 64 + lane];
  float a_own = a0_i[b * 8 + rrow];
  float t0 = wave_sum(v * z);
  float w = z - 2.0f * t0 * v;
  float a_s[8];
  a_s[0] = rlane(a_own, 0);  a_s[1] = rlane(a_own, 2);
  a_s[2] = rlane(a_own, 4);  a_s[3] = rlane(a_own, 6);
  a_s[4] = rlane(a_own, 32); a_s[5] = rlane(a_own, 34);
  a_s[6] = rlane(a_own, 36); a_s[7] = rlane(a_own, 38);

  float* ab = atraj + (size_t)b * (PP * 8);
  uint32_t* zb = ztraj + (size_t)b * (PP * NN);
  bool astore = (lane & 0x19) == 0;   // lanes {0,2,4,6,32,34,36,38}

  auto step_rec = [&]() {
    // h = silu(nb0 + W0 a)
    float u0 = w0r[0] * a_s[0] + w0r[1] * a_s[1];
    float u1 = w0r[2] * a_s[2] + w0r[3] * a_s[3];
    float u2 = w0r[4] * a_s[4] + w0r[5] * a_s[5];
    float u3 = w0r[6] * a_s[6] + w0r[7] * a_s[7];
    float h = siluf(nb0 + ((u0 + u1) + (u2 + u3)));
    // gather over M = {0,1,2,3,32,33,34,35}: DPP + one permlane32
    float hv1 = dppmov<0xB1>(h);
    float hv2 = dppmov<0x4E>(h);
    float hv3 = dppmov<0x1B>(h);
    float slo = (wxl[0] * h + wxl[1] * hv1) + (wxl[2] * hv2 + wxl[3] * hv3);
    float pre = (wxp[0] * h + wxp[1] * hv1) + (wxp[2] * hv2 + wxp[3] * hv3);
    float ps = slo + movswap32(pre, hi32);
    // reduce over S = span{7,8,16}: all VALU
    ps = dppadd<0x141>(ps);
    ps = dppadd<0x128>(ps);
    ps = addswap16(ps);
    float da = tanhf_fast(ps + nb1r);
    // d chain (independent; i8-labeled as before)
    float e0 = g0r[0] * a_s[0] + g0r[1] * a_s[1];
    float e1 = g0r[2] * a_s[2] + g0r[3] * a_s[3];
    float e2 = g0r[4] * a_s[4] + g0r[5] * a_s[5];
    float e3 = g0r[6] * a_s[6] + g0r[7] * a_s[7];
    float g_own = siluf(lb0o + ((e0 + e1) + (e2 + e3)));
    float f0 = d1r[0] * rlane(g_own, 0) + d1r[1] * rlane(g_own, 1);
    float f1 = d1r[2] * rlane(g_own, 2) + d1r[3] * rlane(g_own, 3);
    float f2 = d1r[4] * rlane(g_own, 4) + d1r[5] * rlane(g_own, 5);
    float f3 = d1r[6] * rlane(g_own, 6) + d1r[7] * rlane(g_own, 7);
    float d = lb1 + ((f0 + f1) + (f2 + f3));
    // state update
    a_own += dt * da;
    a_s[0] = rlane(a_own, 0);  a_s[1] = rlane(a_own, 2);
    a_s[2] = rlane(a_own, 4);  a_s[3] = rlane(a_own, 6);
    a_s[4] = rlane(a_own, 32); a_s[5] = rlane(a_own, 34);
    a_s[6] = rlane(a_own, 36); a_s[7] = rlane(a_own, 38);
    w *= (1.0f + dt * d);
  };

  step_rec();                 // step 0
  float wo = w, ao = a_own;
  #pragma unroll 1
  for (int p = 1; p < PP; ++p) {
    float woc = wo, aoc = ao;
    step_rec();               // recurrence for step p (chain)
    wo = w; ao = a_own;
    // output row p-1 (independent of the recurrence above; scheduler
    // interleaves its all-VALU wave_sum with the step's chain)
    float t1 = wave_sum(v * woc);
    float zv = woc - 2.0f * t1 * v;
    if (astore) ab[(p - 1) * 8 + rrow] = aoc;
    zb[(p - 1) * 64 + lane] = packsplit(zv);
  }
  {
    float t1 = wave_sum(v * wo);
    float zv = wo - 2.0f * t1 * v;
    if (astore) ab[(PP - 1) * 8 + rrow] = ao;
    zb[(PP - 1) * 64 + lane] = packsplit(zv);
  }
}

// --------- K4: post nets, register-resident M + ebuf-aliases-wbuf -----------
// LDS = wbuf only (39.7 KB) -> 4 blocks/CU. Pass-1 results stay in registers
// (C-layout); combine via DPP half-row reduce + ror8 partner pull.
__global__ __launch_bounds__(256, 4) void k_post(
    const float* __restrict__ atraj, const uint32_t* __restrict__ ztraj,
    const float* __restrict__ cw0, const float* __restrict__ cb0,
    const float* __restrict__ cw1, const float* __restrict__ cb1,
    const float* __restrict__ zw0, const float* __restrict__ zb0,
    const float* __restrict__ zw1, const float* __restrict__ zb1,
    float* __restrict__ out)
{
  __shared__ uint32_t wbuf[144 * HSTRIDE];  // 39168 B; rows 0..63 reused as ebuf
  __shared__ float    cw0s[64];
  __shared__ float    cb0s[8];
  __shared__ float    zb0s[64];
  __shared__ float    zb1s[8];

  int tid = threadIdx.x;
  int wave = tid >> 6, lane = tid & 63;
  int quad = lane >> 4, m16 = lane & 15;
  size_t tokBase = (size_t)blockIdx.x * 64;

  // ---- stage all weights once (144 rows x 64) ----
  #pragma unroll
  for (int i = 0; i < 36; ++i) {
    int e = i * 256 + tid;
    int o = e >> 6, k = e & 63;
    float wv;
    if (o < 64)       wv = cw1[(((o >> 3) * 64 + k) << 3) + (o & 7)];
    else if (o < 72)  wv = cb1[(o - 64) * 64 + k];
    else if (o < 136) wv = zw0[(o - 72) * 64 + k];
    else              wv = zw1[(o - 136) * 64 + k];
    wbuf[o * HSTRIDE + k] = packsplit(wv);
  }
  if (tid < 64) cw0s[tid] = cw0[tid];
  if (tid < 8)  cb0s[tid] = cb0[tid];
  if (tid < 64) zb0s[tid] = zb0[tid];
  if (tid < 8)  zb1s[tid] = zb1[tid];
  __syncthreads();

  // ---- A-frags (Z) from global packed ztraj ----
  const uint32_t* zp = ztraj + (tokBase + wave * 16 + m16) * 64;
  short8 Ah[2], Al[2];
  readfrag(zp + quad * 8,      Ah[0], Al[0]);
  readfrag(zp + 32 + quad * 8, Ah[1], Al[1]);

  // ---- pass 1: M (nt 0..3) + ybias (nt 4) -> registers ----
  f32x4 acc1[5];
  #pragma unroll
  for (int nt = 0; nt < 5; ++nt) {
    short8 Bh[2], Bl[2];
    readfrag(wbuf + (nt * 16 + m16) * HSTRIDE + quad * 8,      Bh[0], Bl[0]);
    readfrag(wbuf + (nt * 16 + m16) * HSTRIDE + 32 + quad * 8, Bh[1], Bl[1]);
    f32x4 acc = (f32x4){0.f, 0.f, 0.f, 0.f};
    acc1[nt] = mm_split(acc, Ah, Al, Bh, Bl);
  }
  __syncthreads();  // all pass-1 reads of rows 0..79 done -> rows 0..63 reusable

  // ---- pass 2: E = silu(Z @ zw0^T + zb0) -> ebuf (= wbuf rows 0..63) ----
  uint32_t* ebuf = wbuf;
  #pragma unroll
  for (int nt = 0; nt < 4; ++nt) {
    short8 Bh[2], Bl[2];
    readfrag(wbuf + (72 + nt * 16 + m16) * HSTRIDE + quad * 8,      Bh[0], Bl[0]);
    readfrag(wbuf + (72 + nt * 16 + m16) * HSTRIDE + 32 + quad * 8, Bh[1], Bl[1]);
    f32x4 acc = (f32x4){0.f, 0.f, 0.f, 0.f};
    acc = mm_split(acc, Ah, Al, Bh, Bl);
    int m = nt * 16 + m16;
    float zbv = zb0s[m];
    #pragma unroll
    for (int r = 0; r < 4; ++r) {
      float e = siluf(acc[r] + zbv);
      ebuf[(wave * 16 + quad * 4 + r) * HSTRIDE + m] = packsplit(e);
    }
  }

  // ---- pass 3: add = E @ zw1^T + zb1 (ebuf rows wave-private, in-order) ----
  f32x4 acc3;
  {
    short8 Eh[2], El[2];
    readfrag(ebuf + (wave * 16 + m16) * HSTRIDE + quad * 8,      Eh[0], El[0]);
    readfrag(ebuf + (wave * 16 + m16) * HSTRIDE + 32 + quad * 8, Eh[1], El[1]);
    short8 Bh[2], Bl[2];
    int brow = 136 + (m16 & 7);   // duplicate rows for m16>=8; results unused there
    readfrag(wbuf + brow * HSTRIDE + quad * 8,      Bh[0], Bl[0]);
    readfrag(wbuf + brow * HSTRIDE + 32 + quad * 8, Bh[1], Bl[1]);
    f32x4 acc = (f32x4){0.f, 0.f, 0.f, 0.f};
    acc3 = mm_split(acc, Eh, El, Bh, Bl);
  }

  // ---- in-register combine ----
  // Lane (quad, m16) holds M[t=q*4+r][o=nt*16+m16]; c=nt*2+(m16>>3), j=m16&7.
  // yc[t][c] = sum_j g2[t][j] * M[t][c*8+j]: 8-lane half-row reduce; ror8
  // pulls the other half's c-parity. ybias = acc1[4], add = acc3 (lane c=m16<8).
  int j = m16 & 7;
  float cwj[8];
  #pragma unroll
  for (int i = 0; i < 8; ++i) cwj[i] = cw0s[j * 8 + i];
  float cbj = cb0s[j];
  #pragma unroll
  for (int r = 0; r < 4; ++r) {
    size_t idx = tokBase + wave * 16 + quad * 4 + r;
    const float* ap = atraj + idx * 8;
    float4 a0v = *(const float4*)ap;
    float4 a1v = *(const float4*)(ap + 4);
    float g2v = cbj
      + cwj[0] * a0v.x + cwj[1] * a0v.y + cwj[2] * a0v.z + cwj[3] * a0v.w
      + cwj[4] * a1v.x + cwj[5] * a1v.y + cwj[6] * a1v.z + cwj[7] * a1v.w;
    g2v = siluf(g2v);
    float yc[4], qo[4];
    #pragma unroll
    for (int nt = 0; nt < 4; ++nt) {
      float p = acc1[nt][r] * g2v;
      p = dppadd<0xB1>(p);
      p = dppadd<0x4E>(p);
      p = dppadd<0x141>(p);     // sum over 8-lane half-row
      yc[nt] = p;               // c = nt*2 + (m16>>3)
      qo[nt] = dppmov<0x128>(p);// partner half's value: c = nt*2 + 1-(m16>>3)
    }
    if (m16 < 8) {
      int cc = m16;
      int nt = cc >> 1;
      float ye = (nt == 0) ? yc[0] : (nt == 1) ? yc[1] : (nt == 2) ? yc[2] : yc[3];
      float yo = (nt == 0) ? qo[0] : (nt == 1) ? qo[1] : (nt == 2) ? qo[2] : qo[3];
      float y = (cc & 1) ? yo : ye;
      y += acc1[4][r] + acc3[r] + zb1s[cc];
      out[(size_t)(BB * LL * 8) + idx * 8 + cc] = y;
    }
  }
}

extern "C" void kernel_launch(void* const* d_in, const int* in_sizes, int n_in,
                              void* d_out, int out_size, void* d_ws, size_t ws_size,
                              hipStream_t stream) {
  const float* x      = (const float*)d_in[0];
  const float* xp_w0  = (const float*)d_in[1];
  const float* xp_b0  = (const float*)d_in[2];
  const float* xp_w1  = (const float*)d_in[3];
  const float* xp_b1  = (const float*)d_in[4];
  const float* xp_w2  = (const float*)d_in[5];
  const float* xp_b2  = (const float*)d_in[6];
  const float* xp_w3  = (const float*)d_in[7];
  const float* xp_b3  = (const float*)d_in[8];
  const float* xp_w4  = (const float*)d_in[9];
  const float* xp_b4  = (const float*)d_in[10];
  const float* xpp_w0 = (const float*)d_in[11];
  const float* xpp_b0 = (const float*)d_in[12];
  const float* xpp_w1 = (const float*)d_in[13];
  const float* xpp_b1 = (const float*)d_in[14];
  const float* conv_w = (const float*)d_in[15];
  const float* conv_b = (const float*)d_in[16];
  const float* span_A = (const float*)d_in[17];
  const float* comp_w = (const float*)d_in[18];
  const float* comp_b = (const float*)d_in[19];
  const float* net_w0 = (const float*)d_in[20];
  const float* net_b0 = (const float*)d_in[21];
  const float* net_w1 = (const float*)d_in[22];
  const float* net_b1 = (const float*)d_in[23];
  const float* lo_w0  = (const float*)d_in[24];
  const float* lo_b0  = (const float*)d_in[25];
  const float* lo_w1  = (const float*)d_in[26];
  const float* lo_b1  = (const float*)d_in[27];
  const float* lc_w0  = (const float*)d_in[28];
  const float* lc_b0  = (const float*)d_in[29];
  const float* lc_w1  = (const float*)d_in[30];
  const float* lc_b1  = (const float*)d_in[31];
  const float* lz_w0  = (const float*)d_in[32];
  const float* lz_b0  = (const float*)d_in[33];
  const float* lz_w1  = (const float*)d_in[34];
  const float* lz_b1  = (const float*)d_in[35];

  float*    ws    = (float*)d_ws;
  float*    x_old = ws;                    // (B,L,64) fp32
  uint32_t* ztraj = (uint32_t*)ws;         // (B,P,64) packed u32 — aliases x_old
  float*    atraj = ws + 12582912;         // (B,P,8)
  float*    a0    = ws + 14155776;         // (B,8)
  float*    vv    = a0 + 2048 * 8;         // (B,64)
  float*    z0    = vv + 2048 * 64;        // (B,64)
  float*    out   = (float*)d_out;

  hipLaunchKernelGGL(k_xproj, dim3(1536), dim3(256), 0, stream,
                     x, xp_w0, xp_b0, xp_w1, xp_b1, xp_w2, xp_b2, xp_w3, xp_b3,
                     xp_w4, xp_b4, x_old, out);
  hipLaunchKernelGGL(k_hist, dim3(2048), dim3(256), 0, stream,
                     x_old, conv_w, conv_b, comp_w, comp_b,
                     xpp_w0, xpp_b0, xpp_w1, xpp_b1, a0, vv, z0);
  hipLaunchKernelGGL(k_scan, dim3(512), dim3(256), 0, stream,
                     a0, vv, z0, net_w0, net_b0, net_w1, net_b1,
                     lo_w0, lo_b0, lo_w1, lo_b1, span_A, atraj, ztraj);
  hipLaunchKernelGGL(k_post, dim3(3072), dim3(256), 0, stream,
                     atraj, ztraj, lc_w0, lc_b0, lc_w1, lc_b1,
                     lz_w0, lz_b0, lz_w1, lz_b1, out);
}

// Round 4
// 297.386 us; speedup vs baseline: 1.0485x; 1.0212x over previous
//
#include <hip/hip_runtime.h>
#include <cstdint>
#include <cstddef>

#define BB 2048
#define LL 96
#define PP 96
#define NN 64
#define HSTRIDE 68   // u32 row stride for packed LDS tiles (64 + 4 pad, 16B-aligned)

typedef __attribute__((ext_vector_type(8))) short short8;  // 8 bf16 (4 VGPRs)
typedef __attribute__((ext_vector_type(4))) float f32x4;

union U4S8 { uint4 u; short8 s; };

__device__ __forceinline__ float siluf(float x) {
  return x * __builtin_amdgcn_rcpf(1.0f + __expf(-x));
}
__device__ __forceinline__ float tanhf_fast(float x) {
  return 1.0f - 2.0f * __builtin_amdgcn_rcpf(1.0f + __expf(2.0f * x));
}
__device__ __forceinline__ float rlane(float x, int l) {
  return __int_as_float(__builtin_amdgcn_readlane(__float_as_int(x), l));
}

// ---- DPP cross-lane ops (VALU pipe); HW-verified R7/R8 ----
template <int CTRL>
__device__ __forceinline__ float dppadd(float x) {
  int y = __builtin_amdgcn_update_dpp(0, __float_as_int(x), CTRL, 0xF, 0xF, false);
  return x + __int_as_float(y);
}
template <int CTRL>
__device__ __forceinline__ float dppmov(float x) {
  int y = __builtin_amdgcn_update_dpp(0, __float_as_int(x), CTRL, 0xF, 0xF, false);
  return __int_as_float(y);
}

// ---- permlane16/32_swap: VALU-pipe xor16/xor32 (gfx950). With both inputs
// equal to x, out0+out1 == x + x^{16,32} for EVERY lane (no select needed).
__device__ __forceinline__ float addswap16(float x) {
#if __has_builtin(__builtin_amdgcn_permlane16_swap)
  auto r = __builtin_amdgcn_permlane16_swap(__float_as_uint(x), __float_as_uint(x), false, false);
  return __uint_as_float(r[0]) + __uint_as_float(r[1]);
#else
  return x + __shfl_xor(x, 16, 64);
#endif
}
__device__ __forceinline__ float addswap32(float x) {
#if __has_builtin(__builtin_amdgcn_permlane32_swap)
  auto r = __builtin_amdgcn_permlane32_swap(__float_as_uint(x), __float_as_uint(x), false, false);
  return __uint_as_float(r[0]) + __uint_as_float(r[1]);
#else
  return x + __shfl_xor(x, 32, 64);
#endif
}
// value at lane^32 (hi = lane>=32): one permlane + cndmask, VALU pipe.
__device__ __forceinline__ float movswap32(float x, bool hi) {
#if __has_builtin(__builtin_amdgcn_permlane32_swap)
  auto r = __builtin_amdgcn_permlane32_swap(__float_as_uint(x), __float_as_uint(x), false, false);
  return __uint_as_float(hi ? r[0] : r[1]);
#else
  return __shfl_xor(x, 32, 64);
#endif
}

__device__ __forceinline__ float wave_sum(float x) {
  x = dppadd<0xB1>(x);    // ^1
  x = dppadd<0x4E>(x);    // ^2
  x = dppadd<0x141>(x);   // ^7 (row_half_mirror) -> octet sums
  x = dppadd<0x128>(x);   // ^8 (row_ror:8) -> 16-row sums
  x = addswap16(x);       // ^16 (VALU permlane)
  x = addswap32(x);       // ^32 (VALU permlane)
  return x;
}

// split fp32 -> (bf16 hi | bf16 lo) packed in one u32 (hi in top 16).
__device__ __forceinline__ uint32_t packsplit(float f) {
  uint32_t b = __float_as_uint(f);
  uint32_t h = b & 0xFFFF0000u;
  float r = f - __uint_as_float(h);
  return h | (__float_as_uint(r) >> 16);
}
// fp32 -> interleaved pair: low short = hi-bf16 (k-slot 2w), high short =
// lo-bf16 (k-slot 2w+1). A straight MFMA over this layout computes
// Ah*Bh + Al*Bl; pairing with a 16-bit-rotated A gives Al*Bh + Ah*Bl.
__device__ __forceinline__ uint32_t packpair(float f) {
  uint32_t b = __float_as_uint(f);
  uint32_t h = b & 0xFFFF0000u;
  float r = f - __uint_as_float(h);
  return (h >> 16) | (__float_as_uint(r) & 0xFFFF0000u);
}
__device__ __forceinline__ uint32_t rot16(uint32_t x) {
#if __has_builtin(__builtin_amdgcn_alignbit)
  return __builtin_amdgcn_alignbit(x, x, 16);
#else
  return (x >> 16) | (x << 16);
#endif
}
__device__ __forceinline__ uint4 rot16x4(uint4 u) {
  return make_uint4(rot16(u.x), rot16(u.y), rot16(u.z), rot16(u.w));
}
__device__ __forceinline__ short8 as8(uint4 u) { U4S8 c; c.u = u; return c.s; }

__device__ __forceinline__ void splitpack2(float f0, float f1, uint32_t& dhi, uint32_t& dlo) {
  uint32_t b0 = __float_as_uint(f0), b1 = __float_as_uint(f1);
  uint32_t h0 = b0 & 0xFFFF0000u, h1 = b1 & 0xFFFF0000u;
  float r0 = f0 - __uint_as_float(h0), r1 = f1 - __uint_as_float(h1);
  dhi = (h0 >> 16) | h1;
  dlo = (__float_as_uint(r0) >> 16) | (__float_as_uint(r1) & 0xFFFF0000u);
}
__device__ __forceinline__ void unpack2(uint32_t p0, uint32_t p1, uint32_t& dhi, uint32_t& dlo) {
  dhi = (p0 >> 16) | (p1 & 0xFFFF0000u);
  dlo = (p0 & 0xFFFFu) | (p1 << 16);
}
__device__ __forceinline__ void readfrag(const uint32_t* p, short8& hi, short8& lo) {
  uint4 pa = *(const uint4*)p;
  uint4 pb = *(const uint4*)(p + 4);
  U4S8 h, l;
  unpack2(pa.x, pa.y, h.u.x, l.u.x);
  unpack2(pa.z, pa.w, h.u.y, l.u.y);
  unpack2(pb.x, pb.y, h.u.z, l.u.z);
  unpack2(pb.z, pb.w, h.u.w, l.u.w);
  hi = h.s; lo = l.s;
}
// 3-term split-bf16 product over 2 k-steps: acc += A*B (~fp32 accuracy)
__device__ __forceinline__ f32x4 mm_split(f32x4 acc, const short8* Ah, const short8* Al,
                                          const short8* Bh, const short8* Bl) {
  acc = __builtin_amdgcn_mfma_f32_16x16x32_bf16(Ah[0], Bh[0], acc, 0, 0, 0);
  acc = __builtin_amdgcn_mfma_f32_16x16x32_bf16(Ah[1], Bh[1], acc, 0, 0, 0);
  acc = __builtin_amdgcn_mfma_f32_16x16x32_bf16(Al[0], Bh[0], acc, 0, 0, 0);
  acc = __builtin_amdgcn_mfma_f32_16x16x32_bf16(Al[1], Bh[1], acc, 0, 0, 0);
  acc = __builtin_amdgcn_mfma_f32_16x16x32_bf16(Ah[0], Bl[0], acc, 0, 0, 0);
  acc = __builtin_amdgcn_mfma_f32_16x16x32_bf16(Ah[1], Bl[1], acc, 0, 0, 0);
  return acc;
}

// ---------------- K1: x_proj (R12: interleaved-pair LDS, no unpack) ---------
// R11 PMC: MfmaUtil 15%, VALUBusy 50% -> the readfrag unpack tax (~240 VALU
// ops/wave/layer) dominated. R12 stores every element as u32 with its hi/lo
// bf16 halves in ADJACENT k-slots: fragment reads are raw ds_read_b128 (zero
// VALU), straight MFMA gives Ah*Bh+Al*Bl, rot16(A) MFMA adds Al*Bh+Ah*Bl
// (exact 4-term product; K doubles -> 8 MFMA per 16x16 tile pair vs 6).
__global__ __launch_bounds__(256, 2) void k_xproj(
    const float* __restrict__ x,
    const float* __restrict__ w0, const float* __restrict__ b0,
    const float* __restrict__ w1, const float* __restrict__ b1,
    const float* __restrict__ w2, const float* __restrict__ b2,
    const float* __restrict__ w3, const float* __restrict__ b3,
    const float* __restrict__ w4, const float* __restrict__ b4,
    float* __restrict__ x_old, float* __restrict__ out)
{
  __shared__ uint32_t hbuf[128 * HSTRIDE];
  __shared__ uint32_t wbufA[64 * HSTRIDE];
  __shared__ uint32_t wbufB[64 * HSTRIDE];
  __shared__ float bs[320];

  int tid = threadIdx.x;
  int wave = tid >> 6, lane = tid & 63;
  int quad = lane >> 4, m16 = lane & 15;
  size_t tokBase = (size_t)blockIdx.x * 128;

  {
    size_t e = tokBase * 8 + (size_t)tid * 4;
    *(float4*)(out + e) = *(const float4*)(x + e);
  }
  if (tid < 64) {
    bs[tid]       = b0[tid];
    bs[64 + tid]  = b1[tid];
    bs[128 + tid] = b2[tid];
    bs[192 + tid] = b3[tid];
    bs[256 + tid] = b4[tid];
  }
  #pragma unroll
  for (int i = 0; i < 4; ++i) {
    int e4 = i * 256 + tid;
    int o = e4 >> 4, k = (e4 & 15) << 2;
    float4 wv = ((const float4*)w1)[e4];
    *(uint4*)(wbufA + o * HSTRIDE + k) =
        make_uint4(packpair(wv.x), packpair(wv.y), packpair(wv.z), packpair(wv.w));
  }
  __syncthreads();

  // ---- layer 0: K=8 (16 slots, quads 0..1 carry data) ----
  uint4 A0[2];
  #pragma unroll
  for (int mt = 0; mt < 2; ++mt) {
    uint4 t = make_uint4(0, 0, 0, 0);
    if (quad < 2) {
      const float* xp = x + (tokBase + wave * 32 + mt * 16 + m16) * 8 + quad * 4;
      float4 xa = *(const float4*)xp;
      t = make_uint4(packpair(xa.x), packpair(xa.y), packpair(xa.z), packpair(xa.w));
    }
    A0[mt] = t;
  }
  uint4 B0[4];
  #pragma unroll
  for (int nt = 0; nt < 4; ++nt) {
    uint4 t = make_uint4(0, 0, 0, 0);
    if (quad < 2) {
      const float* wp = w0 + (nt * 16 + m16) * 8 + quad * 4;
      float4 wa = *(const float4*)wp;
      t = make_uint4(packpair(wa.x), packpair(wa.y), packpair(wa.z), packpair(wa.w));
    }
    B0[nt] = t;
  }
  {
    f32x4 acc[2][4];
    #pragma unroll
    for (int mt = 0; mt < 2; ++mt)
      #pragma unroll
      for (int nt = 0; nt < 4; ++nt) {
        float bv = bs[nt * 16 + m16];
        acc[mt][nt] = (f32x4){bv, bv, bv, bv};
      }
    #pragma unroll
    for (int mt = 0; mt < 2; ++mt)
      #pragma unroll
      for (int nt = 0; nt < 4; ++nt)
        acc[mt][nt] = __builtin_amdgcn_mfma_f32_16x16x32_bf16(as8(A0[mt]), as8(B0[nt]), acc[mt][nt], 0, 0, 0);
    #pragma unroll
    for (int mt = 0; mt < 2; ++mt) {
      uint4 As = rot16x4(A0[mt]);
      #pragma unroll
      for (int nt = 0; nt < 4; ++nt)
        acc[mt][nt] = __builtin_amdgcn_mfma_f32_16x16x32_bf16(as8(As), as8(B0[nt]), acc[mt][nt], 0, 0, 0);
    }
    #pragma unroll
    for (int mt = 0; mt < 2; ++mt)
      #pragma unroll
      for (int nt = 0; nt < 4; ++nt)
        #pragma unroll
        for (int r = 0; r < 4; ++r) {
          float s = siluf(acc[mt][nt][r]);
          hbuf[(wave * 32 + mt * 16 + quad * 4 + r) * HSTRIDE + nt * 16 + m16] = packpair(s);
        }
  }

  const float* Ws[4] = {w1, w2, w3, w4};
  uint32_t* cur = wbufA;
  uint32_t* nxt = wbufB;
  #pragma unroll 1
  for (int lyr = 0; lyr < 4; ++lyr) {
    float4 wv[4];
    if (lyr < 3) {
      const float* wn = Ws[lyr + 1];
      #pragma unroll
      for (int i = 0; i < 4; ++i) wv[i] = ((const float4*)wn)[i * 256 + tid];
    }
    // fragment reads: raw b128, no unpack
    uint4 Bf[16];
    #pragma unroll
    for (int nt = 0; nt < 4; ++nt)
      #pragma unroll
      for (int c = 0; c < 4; ++c)
        Bf[nt * 4 + c] = *(const uint4*)(cur + (nt * 16 + m16) * HSTRIDE + c * 16 + quad * 4);
    uint4 Af[8];
    #pragma unroll
    for (int mt = 0; mt < 2; ++mt)
      #pragma unroll
      for (int c = 0; c < 4; ++c)
        Af[mt * 4 + c] = *(const uint4*)(hbuf + (wave * 32 + mt * 16 + m16) * HSTRIDE + c * 16 + quad * 4);

    f32x4 acc[2][4];
    #pragma unroll
    for (int mt = 0; mt < 2; ++mt)
      #pragma unroll
      for (int nt = 0; nt < 4; ++nt) {
        float bv = bs[(lyr + 1) * 64 + nt * 16 + m16];
        acc[mt][nt] = (f32x4){bv, bv, bv, bv};
      }
    #pragma unroll
    for (int c = 0; c < 4; ++c)
      #pragma unroll
      for (int mt = 0; mt < 2; ++mt)
        #pragma unroll
        for (int nt = 0; nt < 4; ++nt)
          acc[mt][nt] = __builtin_amdgcn_mfma_f32_16x16x32_bf16(as8(Af[mt * 4 + c]), as8(Bf[nt * 4 + c]), acc[mt][nt], 0, 0, 0);
    #pragma unroll
    for (int c = 0; c < 4; ++c)
      #pragma unroll
      for (int mt = 0; mt < 2; ++mt) {
        uint4 As = rot16x4(Af[mt * 4 + c]);
        #pragma unroll
        for (int nt = 0; nt < 4; ++nt)
          acc[mt][nt] = __builtin_amdgcn_mfma_f32_16x16x32_bf16(as8(As), as8(Bf[nt * 4 + c]), acc[mt][nt], 0, 0, 0);
      }

    if (lyr < 3) {
      #pragma unroll
      for (int i = 0; i < 4; ++i) {
        int e4 = i * 256 + tid;
        int o = e4 >> 4, k = (e4 & 15) << 2;
        *(uint4*)(nxt + o * HSTRIDE + k) =
            make_uint4(packpair(wv[i].x), packpair(wv[i].y), packpair(wv[i].z), packpair(wv[i].w));
      }
    }

    if (lyr < 3) {
      #pragma unroll
      for (int mt = 0; mt < 2; ++mt)
        #pragma unroll
        for (int nt = 0; nt < 4; ++nt)
          #pragma unroll
          for (int r = 0; r < 4; ++r) {
            float s = siluf(acc[mt][nt][r]);
            hbuf[(wave * 32 + mt * 16 + quad * 4 + r) * HSTRIDE + nt * 16 + m16] = packpair(s);
          }
    } else {
      #pragma unroll
      for (int mt = 0; mt < 2; ++mt)
        #pragma unroll
        for (int nt = 0; nt < 4; ++nt)
          #pragma unroll
          for (int r = 0; r < 4; ++r) {
            size_t t = tokBase + wave * 32 + mt * 16 + quad * 4 + r;
            x_old[t * 64 + nt * 16 + m16] = acc[mt][nt][r];
          }
    }
    __syncthreads();
    uint32_t* tmp = cur; cur = nxt; nxt = tmp;
  }
}

// ------- K2: per-batch conv + compression + v + z0 (R8 version) -------------
__global__ __launch_bounds__(256) void k_hist(
    const float* __restrict__ x_old,
    const float* __restrict__ conv_w, const float* __restrict__ conv_b,
    const float* __restrict__ comp_w, const float* __restrict__ comp_b,
    const float* __restrict__ xw0, const float* __restrict__ xb0,
    const float* __restrict__ xw1, const float* __restrict__ xb1,
    float* __restrict__ a0_o, float* __restrict__ v_o, float* __restrict__ z0_o)
{
  __shared__ float xo[LL * NN];
  __shared__ float red[32];
  __shared__ float hbuf[64];
  int b = blockIdx.x, tid = threadIdx.x;
  const float* src = x_old + (size_t)b * (LL * NN);
  #pragma unroll
  for (int i = 0; i < 6; ++i) {
    int e = (i * 256 + tid) * 4;
    *(float4*)(xo + e) = *(const float4*)(src + e);
  }
  __syncthreads();
  int c = tid & 63;
  float cw0 = conv_w[c * 3], cw1 = conv_w[c * 3 + 1], cw2 = conv_w[c * 3 + 2];
  float cb = conv_b[c];
  float acc[8];
  #pragma unroll
  for (int q = 0; q < 8; ++q) acc[q] = 0.f;
  #pragma unroll 1
  for (int j = 0; j < 24; ++j) {
    int e = j * 256 + tid;
    int t = e >> 6;
    float s = xo[t * 64 + c] * cw0 + cb;
    if (t + 2 < LL) s += xo[(t + 2) * 64 + c] * cw1;
    if (t + 4 < LL) s += xo[(t + 4) * 64 + c] * cw2;
    float hv = siluf(s);
    #pragma unroll
    for (int q = 0; q < 8; ++q) acc[q] += hv * comp_w[q * 6144 + e];
  }
  #pragma unroll
  for (int q = 0; q < 8; ++q) acc[q] = dppadd<0xB1>(acc[q]);
  #pragma unroll
  for (int q = 0; q < 8; ++q) acc[q] = dppadd<0x4E>(acc[q]);
  #pragma unroll
  for (int q = 0; q < 8; ++q) acc[q] = dppadd<0x141>(acc[q]);
  #pragma unroll
  for (int q = 0; q < 8; ++q) acc[q] = dppadd<0x128>(acc[q]);
  #pragma unroll
  for (int q = 0; q < 8; ++q) acc[q] = addswap16(acc[q]);
  #pragma unroll
  for (int q = 0; q < 8; ++q) acc[q] = addswap32(acc[q]);
  int wave = tid >> 6, lane = tid & 63;
  if (lane < 8) {
    float sel = acc[0];
    #pragma unroll
    for (int q = 1; q < 8; ++q) sel = (lane == q) ? acc[q] : sel;
    red[wave * 8 + lane] = sel;
  }
  __syncthreads();
  if (tid < 8)
    a0_o[b * 8 + tid] = red[tid] + red[8 + tid] + red[16 + tid] + red[24 + tid] + comp_b[tid];
  if (tid < 64) {
    float a2 = xb0[tid];
    #pragma unroll 8
    for (int k = 0; k < 64; ++k) a2 += xw0[tid * 64 + k] * xo[6080 + k];
    hbuf[tid] = siluf(a2);
  }
  __syncthreads();
  float vr = 0.f;
  if (tid < 64) {
    vr = xb1[tid];
    #pragma unroll 8
    for (int k = 0; k < 64; ++k) vr += xw1[tid * 64 + k] * hbuf[k];
  }
  float s2 = wave_sum(vr * vr);
  if (tid < 64) {
    float nrm = sqrtf(s2) + 1e-8f;
    v_o[b * 64 + tid] = vr / nrm;
    z0_o[b * 64 + tid] = xo[6080 + tid];
  }
}

// ------------- K3: 96-step ODE scan (R11: all-VALU cross-lane) --------------
__global__ __launch_bounds__(256) void k_scan(
    const float* __restrict__ a0_i, const float* __restrict__ v_i, const float* __restrict__ z0_i,
    const float* __restrict__ nw0, const float* __restrict__ nb0_p,
    const float* __restrict__ nw1, const float* __restrict__ nb1_p,
    const float* __restrict__ lw0, const float* __restrict__ lb0_p,
    const float* __restrict__ lw1, const float* __restrict__ lb1_p,
    const float* __restrict__ spanA, float* __restrict__ atraj, uint32_t* __restrict__ ztraj)
{
  int tid = threadIdx.x;
  int lane = tid & 63;
  int wv = tid >> 6;
  int b = blockIdx.x * 4 + wv;
  float dt = fminf(fmaxf(spanA[0], 1e-8f), 7.0f);
  int i8 = lane & 7;
  bool hi32 = lane >= 32;
  // output-row label, constant on span{7,8,16}-cosets
  int rrow = ((lane ^ (lane >> 1)) & 1) | (((lane ^ (lane >> 2)) & 1) << 1) | (((lane >> 5) & 1) << 2);

  float w0r[8], wxl[4], wxp[4], g0r[8], d1r[8];
  #pragma unroll
  for (int i = 0; i < 8; ++i) w0r[i] = nw0[lane * 8 + i];
  #pragma unroll
  for (int j = 0; j < 4; ++j) wxl[j] = nw1[rrow * 64 + (lane ^ j)];
  #pragma unroll
  for (int j = 0; j < 4; ++j) wxp[j] = nw1[(rrow ^ 4) * 64 + (lane ^ j)];
  #pragma unroll
  for (int i = 0; i < 8; ++i) g0r[i] = lw0[i8 * 8 + i];
  #pragma unroll
  for (int i = 0; i < 8; ++i) d1r[i] = lw1[lane * 8 + i];
  float nb0 = nb0_p[lane];
  float nb1r = nb1_p[rrow];
  float lb0o = lb0_p[i8];
  float lb1 = lb1_p[lane];
  float v = v_i[b * 64 + lane];
  float z = z0_i[b * 64 + lane];
  float a_own = a0_i[b * 8 + rrow];
  float t0 = wave_sum(v * z);
  float w = z - 2.0f * t0 * v;
  float a_s[8];
  a_s[0] = rlane(a_own, 0);  a_s[1] = rlane(a_own, 2);
  a_s[2] = rlane(a_own, 4);  a_s[3] = rlane(a_own, 6);
  a_s[4] = rlane(a_own, 32); a_s[5] = rlane(a_own, 34);
  a_s[6] = rlane(a_own, 36); a_s[7] = rlane(a_own, 38);

  float* ab = atraj + (size_t)b * (PP * 8);
  uint32_t* zb = ztraj + (size_t)b * (PP * NN);
  bool astore = (lane & 0x19) == 0;   // lanes {0,2,4,6,32,34,36,38}

  auto step_rec = [&]() {
    // h = silu(nb0 + W0 a)
    float u0 = w0r[0] * a_s[0] + w0r[1] * a_s[1];
    float u1 = w0r[2] * a_s[2] + w0r[3] * a_s[3];
    float u2 = w0r[4] * a_s[4] + w0r[5] * a_s[5];
    float u3 = w0r[6] * a_s[6] + w0r[7] * a_s[7];
    float h = siluf(nb0 + ((u0 + u1) + (u2 + u3)));
    // gather over M = {0,1,2,3,32,33,34,35}: DPP + one permlane32
    float hv1 = dppmov<0xB1>(h);
    float hv2 = dppmov<0x4E>(h);
    float hv3 = dppmov<0x1B>(h);
    float slo = (wxl[0] * h + wxl[1] * hv1) + (wxl[2] * hv2 + wxl[3] * hv3);
    float pre = (wxp[0] * h + wxp[1] * hv1) + (wxp[2] * hv2 + wxp[3] * hv3);
    float ps = slo + movswap32(pre, hi32);
    // reduce over S = span{7,8,16}: all VALU
    ps = dppadd<0x141>(ps);
    ps = dppadd<0x128>(ps);
    ps = addswap16(ps);
    float da = tanhf_fast(ps + nb1r);
    // d chain (independent; i8-labeled as before)
    float e0 = g0r[0] * a_s[0] + g0r[1] * a_s[1];
    float e1 = g0r[2] * a_s[2] + g0r[3] * a_s[3];
    float e2 = g0r[4] * a_s[4] + g0r[5] * a_s[5];
    float e3 = g0r[6] * a_s[6] + g0r[7] * a_s[7];
    float g_own = siluf(lb0o + ((e0 + e1) + (e2 + e3)));
    float f0 = d1r[0] * rlane(g_own, 0) + d1r[1] * rlane(g_own, 1);
    float f1 = d1r[2] * rlane(g_own, 2) + d1r[3] * rlane(g_own, 3);
    float f2 = d1r[4] * rlane(g_own, 4) + d1r[5] * rlane(g_own, 5);
    float f3 = d1r[6] * rlane(g_own, 6) + d1r[7] * rlane(g_own, 7);
    float d = lb1 + ((f0 + f1) + (f2 + f3));
    // state update
    a_own += dt * da;
    a_s[0] = rlane(a_own, 0);  a_s[1] = rlane(a_own, 2);
    a_s[2] = rlane(a_own, 4);  a_s[3] = rlane(a_own, 6);
    a_s[4] = rlane(a_own, 32); a_s[5] = rlane(a_own, 34);
    a_s[6] = rlane(a_own, 36); a_s[7] = rlane(a_own, 38);
    w *= (1.0f + dt * d);
  };

  step_rec();                 // step 0
  float wo = w, ao = a_own;
  #pragma unroll 1
  for (int p = 1; p < PP; ++p) {
    float woc = wo, aoc = ao;
    step_rec();               // recurrence for step p (chain)
    wo = w; ao = a_own;
    // output row p-1 (independent of the recurrence above; scheduler
    // interleaves its all-VALU wave_sum with the step's chain)
    float t1 = wave_sum(v * woc);
    float zv = woc - 2.0f * t1 * v;
    if (astore) ab[(p - 1) * 8 + rrow] = aoc;
    zb[(p - 1) * 64 + lane] = packsplit(zv);
  }
  {
    float t1 = wave_sum(v * wo);
    float zv = wo - 2.0f * t1 * v;
    if (astore) ab[(PP - 1) * 8 + rrow] = ao;
    zb[(PP - 1) * 64 + lane] = packsplit(zv);
  }
}

// --------- K4: post nets, register-resident M + ebuf-aliases-wbuf -----------
// LDS = wbuf only (39.7 KB) -> 4 blocks/CU. Pass-1 results stay in registers
// (C-layout); combine via DPP half-row reduce + ror8 partner pull.
__global__ __launch_bounds__(256, 4) void k_post(
    const float* __restrict__ atraj, const uint32_t* __restrict__ ztraj,
    const float* __restrict__ cw0, const float* __restrict__ cb0,
    const float* __restrict__ cw1, const float* __restrict__ cb1,
    const float* __restrict__ zw0, const float* __restrict__ zb0,
    const float* __restrict__ zw1, const float* __restrict__ zb1,
    float* __restrict__ out)
{
  __shared__ uint32_t wbuf[144 * HSTRIDE];  // 39168 B; rows 0..63 reused as ebuf
  __shared__ float    cw0s[64];
  __shared__ float    cb0s[8];
  __shared__ float    zb0s[64];
  __shared__ float    zb1s[8];

  int tid = threadIdx.x;
  int wave = tid >> 6, lane = tid & 63;
  int quad = lane >> 4, m16 = lane & 15;
  size_t tokBase = (size_t)blockIdx.x * 64;

  // ---- stage all weights once (144 rows x 64) ----
  #pragma unroll
  for (int i = 0; i < 36; ++i) {
    int e = i * 256 + tid;
    int o = e >> 6, k = e & 63;
    float wv;
    if (o < 64)       wv = cw1[(((o >> 3) * 64 + k) << 3) + (o & 7)];
    else if (o < 72)  wv = cb1[(o - 64) * 64 + k];
    else if (o < 136) wv = zw0[(o - 72) * 64 + k];
    else              wv = zw1[(o - 136) * 64 + k];
    wbuf[o * HSTRIDE + k] = packsplit(wv);
  }
  if (tid < 64) cw0s[tid] = cw0[tid];
  if (tid < 8)  cb0s[tid] = cb0[tid];
  if (tid < 64) zb0s[tid] = zb0[tid];
  if (tid < 8)  zb1s[tid] = zb1[tid];
  __syncthreads();

  // ---- A-frags (Z) from global packed ztraj ----
  const uint32_t* zp = ztraj + (tokBase + wave * 16 + m16) * 64;
  short8 Ah[2], Al[2];
  readfrag(zp + quad * 8,      Ah[0], Al[0]);
  readfrag(zp + 32 + quad * 8, Ah[1], Al[1]);

  // ---- pass 1: M (nt 0..3) + ybias (nt 4) -> registers ----
  f32x4 acc1[5];
  #pragma unroll
  for (int nt = 0; nt < 5; ++nt) {
    short8 Bh[2], Bl[2];
    readfrag(wbuf + (nt * 16 + m16) * HSTRIDE + quad * 8,      Bh[0], Bl[0]);
    readfrag(wbuf + (nt * 16 + m16) * HSTRIDE + 32 + quad * 8, Bh[1], Bl[1]);
    f32x4 acc = (f32x4){0.f, 0.f, 0.f, 0.f};
    acc1[nt] = mm_split(acc, Ah, Al, Bh, Bl);
  }
  __syncthreads();  // all pass-1 reads of rows 0..79 done -> rows 0..63 reusable

  // ---- pass 2: E = silu(Z @ zw0^T + zb0) -> ebuf (= wbuf rows 0..63) ----
  uint32_t* ebuf = wbuf;
  #pragma unroll
  for (int nt = 0; nt < 4; ++nt) {
    short8 Bh[2], Bl[2];
    readfrag(wbuf + (72 + nt * 16 + m16) * HSTRIDE + quad * 8,      Bh[0], Bl[0]);
    readfrag(wbuf + (72 + nt * 16 + m16) * HSTRIDE + 32 + quad * 8, Bh[1], Bl[1]);
    f32x4 acc = (f32x4){0.f, 0.f, 0.f, 0.f};
    acc = mm_split(acc, Ah, Al, Bh, Bl);
    int m = nt * 16 + m16;
    float zbv = zb0s[m];
    #pragma unroll
    for (int r = 0; r < 4; ++r) {
      float e = siluf(acc[r] + zbv);
      ebuf[(wave * 16 + quad * 4 + r) * HSTRIDE + m] = packsplit(e);
    }
  }

  // ---- pass 3: add = E @ zw1^T + zb1 (ebuf rows wave-private, in-order) ----
  f32x4 acc3;
  {
    short8 Eh[2], El[2];
    readfrag(ebuf + (wave * 16 + m16) * HSTRIDE + quad * 8,      Eh[0], El[0]);
    readfrag(ebuf + (wave * 16 + m16) * HSTRIDE + 32 + quad * 8, Eh[1], El[1]);
    short8 Bh[2], Bl[2];
    int brow = 136 + (m16 & 7);   // duplicate rows for m16>=8; results unused there
    readfrag(wbuf + brow * HSTRIDE + quad * 8,      Bh[0], Bl[0]);
    readfrag(wbuf + brow * HSTRIDE + 32 + quad * 8, Bh[1], Bl[1]);
    f32x4 acc = (f32x4){0.f, 0.f, 0.f, 0.f};
    acc3 = mm_split(acc, Eh, El, Bh, Bl);
  }

  // ---- in-register combine ----
  // Lane (quad, m16) holds M[t=q*4+r][o=nt*16+m16]; c=nt*2+(m16>>3), j=m16&7.
  // yc[t][c] = sum_j g2[t][j] * M[t][c*8+j]: 8-lane half-row reduce; ror8
  // pulls the other half's c-parity. ybias = acc1[4], add = acc3 (lane c=m16<8).
  int j = m16 & 7;
  float cwj[8];
  #pragma unroll
  for (int i = 0; i < 8; ++i) cwj[i] = cw0s[j * 8 + i];
  float cbj = cb0s[j];
  #pragma unroll
  for (int r = 0; r < 4; ++r) {
    size_t idx = tokBase + wave * 16 + quad * 4 + r;
    const float* ap = atraj + idx * 8;
    float4 a0v = *(const float4*)ap;
    float4 a1v = *(const float4*)(ap + 4);
    float g2v = cbj
      + cwj[0] * a0v.x + cwj[1] * a0v.y + cwj[2] * a0v.z + cwj[3] * a0v.w
      + cwj[4] * a1v.x + cwj[5] * a1v.y + cwj[6] * a1v.z + cwj[7] * a1v.w;
    g2v = siluf(g2v);
    float yc[4], qo[4];
    #pragma unroll
    for (int nt = 0; nt < 4; ++nt) {
      float p = acc1[nt][r] * g2v;
      p = dppadd<0xB1>(p);
      p = dppadd<0x4E>(p);
      p = dppadd<0x141>(p);     // sum over 8-lane half-row
      yc[nt] = p;               // c = nt*2 + (m16>>3)
      qo[nt] = dppmov<0x128>(p);// partner half's value: c = nt*2 + 1-(m16>>3)
    }
    if (m16 < 8) {
      int cc = m16;
      int nt = cc >> 1;
      float ye = (nt == 0) ? yc[0] : (nt == 1) ? yc[1] : (nt == 2) ? yc[2] : yc[3];
      float yo = (nt == 0) ? qo[0] : (nt == 1) ? qo[1] : (nt == 2) ? qo[2] : qo[3];
      float y = (cc & 1) ? yo : ye;
      y += acc1[4][r] + acc3[r] + zb1s[cc];
      out[(size_t)(BB * LL * 8) + idx * 8 + cc] = y;
    }
  }
}

extern "C" void kernel_launch(void* const* d_in, const int* in_sizes, int n_in,
                              void* d_out, int out_size, void* d_ws, size_t ws_size,
                              hipStream_t stream) {
  const float* x      = (const float*)d_in[0];
  const float* xp_w0  = (const float*)d_in[1];
  const float* xp_b0  = (const float*)d_in[2];
  const float* xp_w1  = (const float*)d_in[3];
  const float* xp_b1  = (const float*)d_in[4];
  const float* xp_w2  = (const float*)d_in[5];
  const float* xp_b2  = (const float*)d_in[6];
  const float* xp_w3  = (const float*)d_in[7];
  const float* xp_b3  = (const float*)d_in[8];
  const float* xp_w4  = (const float*)d_in[9];
  const float* xp_b4  = (const float*)d_in[10];
  const float* xpp_w0 = (const float*)d_in[11];
  const float* xpp_b0 = (const float*)d_in[12];
  const float* xpp_w1 = (const float*)d_in[13];
  const float* xpp_b1 = (const float*)d_in[14];
  const float* conv_w = (const float*)d_in[15];
  const float* conv_b = (const float*)d_in[16];
  const float* span_A = (const float*)d_in[17];
  const float* comp_w = (const float*)d_in[18];
  const float* comp_b = (const float*)d_in[19];
  const float* net_w0 = (const float*)d_in[20];
  const float* net_b0 = (const float*)d_in[21];
  const float* net_w1 = (const float*)d_in[22];
  const float* net_b1 = (const float*)d_in[23];
  const float* lo_w0  = (const float*)d_in[24];
  const float* lo_b0  = (const float*)d_in[25];
  const float* lo_w1  = (const float*)d_in[26];
  const float* lo_b1  = (const float*)d_in[27];
  const float* lc_w0  = (const float*)d_in[28];
  const float* lc_b0  = (const float*)d_in[29];
  const float* lc_w1  = (const float*)d_in[30];
  const float* lc_b1  = (const float*)d_in[31];
  const float* lz_w0  = (const float*)d_in[32];
  const float* lz_b0  = (const float*)d_in[33];
  const float* lz_w1  = (const float*)d_in[34];
  const float* lz_b1  = (const float*)d_in[35];

  float*    ws    = (float*)d_ws;
  float*    x_old = ws;                    // (B,L,64) fp32
  uint32_t* ztraj = (uint32_t*)ws;         // (B,P,64) packed u32 — aliases x_old
  float*    atraj = ws + 12582912;         // (B,P,8)
  float*    a0    = ws + 14155776;         // (B,8)
  float*    vv    = a0 + 2048 * 8;         // (B,64)
  float*    z0    = vv + 2048 * 64;        // (B,64)
  float*    out   = (float*)d_out;

  hipLaunchKernelGGL(k_xproj, dim3(1536), dim3(256), 0, stream,
                     x, xp_w0, xp_b0, xp_w1, xp_b1, xp_w2, xp_b2, xp_w3, xp_b3,
                     xp_w4, xp_b4, x_old, out);
  hipLaunchKernelGGL(k_hist, dim3(2048), dim3(256), 0, stream,
                     x_old, conv_w, conv_b, comp_w, comp_b,
                     xpp_w0, xpp_b0, xpp_w1, xpp_b1, a0, vv, z0);
  hipLaunchKernelGGL(k_scan, dim3(512), dim3(256), 0, stream,
                     a0, vv, z0, net_w0, net_b0, net_w1, net_b1,
                     lo_w0, lo_b0, lo_w1, lo_b1, span_A, atraj, ztraj);
  hipLaunchKernelGGL(k_post, dim3(3072), dim3(256), 0, stream,
                     atraj, ztraj, lc_w0, lc_b0, lc_w1, lc_b1,
                     lz_w0, lz_b0, lz_w1, lz_b1, out);
}

// Round 5
// 296.329 us; speedup vs baseline: 1.0523x; 1.0036x over previous
//
#include <hip/hip_runtime.h>
#include <cstdint>
#include <cstddef>

#define BB 2048
#define LL 96
#define PP 96
#define NN 64
#define HSTRIDE 68   // u32 row stride for packed LDS tiles (64 + 4 pad, 16B-aligned)

typedef __attribute__((ext_vector_type(8))) short short8;  // 8 bf16 (4 VGPRs)
typedef __attribute__((ext_vector_type(4))) float f32x4;

union U4S8 { uint4 u; short8 s; };

__device__ __forceinline__ float siluf(float x) {
  return x * __builtin_amdgcn_rcpf(1.0f + __expf(-x));
}
__device__ __forceinline__ float tanhf_fast(float x) {
  return 1.0f - 2.0f * __builtin_amdgcn_rcpf(1.0f + __expf(2.0f * x));
}
__device__ __forceinline__ float rlane(float x, int l) {
  return __int_as_float(__builtin_amdgcn_readlane(__float_as_int(x), l));
}

// ---- DPP cross-lane ops (VALU pipe); HW-verified R7/R8 ----
template <int CTRL>
__device__ __forceinline__ float dppadd(float x) {
  int y = __builtin_amdgcn_update_dpp(0, __float_as_int(x), CTRL, 0xF, 0xF, false);
  return x + __int_as_float(y);
}
template <int CTRL>
__device__ __forceinline__ float dppmov(float x) {
  int y = __builtin_amdgcn_update_dpp(0, __float_as_int(x), CTRL, 0xF, 0xF, false);
  return __int_as_float(y);
}

// ---- permlane16/32_swap: VALU-pipe xor16/xor32 (gfx950). With both inputs
// equal to x, out0+out1 == x + x^{16,32} for EVERY lane (no select needed).
__device__ __forceinline__ float addswap16(float x) {
#if __has_builtin(__builtin_amdgcn_permlane16_swap)
  auto r = __builtin_amdgcn_permlane16_swap(__float_as_uint(x), __float_as_uint(x), false, false);
  return __uint_as_float(r[0]) + __uint_as_float(r[1]);
#else
  return x + __shfl_xor(x, 16, 64);
#endif
}
__device__ __forceinline__ float addswap32(float x) {
#if __has_builtin(__builtin_amdgcn_permlane32_swap)
  auto r = __builtin_amdgcn_permlane32_swap(__float_as_uint(x), __float_as_uint(x), false, false);
  return __uint_as_float(r[0]) + __uint_as_float(r[1]);
#else
  return x + __shfl_xor(x, 32, 64);
#endif
}
// value at lane^32 (hi = lane>=32): one permlane + cndmask, VALU pipe.
__device__ __forceinline__ float movswap32(float x, bool hi) {
#if __has_builtin(__builtin_amdgcn_permlane32_swap)
  auto r = __builtin_amdgcn_permlane32_swap(__float_as_uint(x), __float_as_uint(x), false, false);
  return __uint_as_float(hi ? r[0] : r[1]);
#else
  return __shfl_xor(x, 32, 64);
#endif
}

__device__ __forceinline__ float wave_sum(float x) {
  x = dppadd<0xB1>(x);    // ^1
  x = dppadd<0x4E>(x);    // ^2
  x = dppadd<0x141>(x);   // ^7 (row_half_mirror) -> octet sums
  x = dppadd<0x128>(x);   // ^8 (row_ror:8) -> 16-row sums
  x = addswap16(x);       // ^16 (VALU permlane)
  x = addswap32(x);       // ^32 (VALU permlane)
  return x;
}

// fp32 -> interleaved pair: low short = hi-bf16 (k-slot 2w), high short =
// lo-bf16 (k-slot 2w+1). A straight MFMA over this layout computes
// Ah*Bh + Al*Bl; pairing with a 16-bit-rotated A gives Al*Bh + Ah*Bl.
// Sum = exact (Ah+Al)*(Bh+Bl) 4-term product, zero unpack VALU.
__device__ __forceinline__ uint32_t packpair(float f) {
  uint32_t b = __float_as_uint(f);
  uint32_t h = b & 0xFFFF0000u;
  float r = f - __uint_as_float(h);
  return (h >> 16) | (__float_as_uint(r) & 0xFFFF0000u);
}
__device__ __forceinline__ uint32_t rot16(uint32_t x) {
#if __has_builtin(__builtin_amdgcn_alignbit)
  return __builtin_amdgcn_alignbit(x, x, 16);
#else
  return (x >> 16) | (x << 16);
#endif
}
__device__ __forceinline__ uint4 rot16x4(uint4 u) {
  return make_uint4(rot16(u.x), rot16(u.y), rot16(u.z), rot16(u.w));
}
__device__ __forceinline__ short8 as8(uint4 u) { U4S8 c; c.u = u; return c.s; }

// ---------------- K1: x_proj (R12: interleaved-pair LDS, no unpack) ---------
__global__ __launch_bounds__(256, 2) void k_xproj(
    const float* __restrict__ x,
    const float* __restrict__ w0, const float* __restrict__ b0,
    const float* __restrict__ w1, const float* __restrict__ b1,
    const float* __restrict__ w2, const float* __restrict__ b2,
    const float* __restrict__ w3, const float* __restrict__ b3,
    const float* __restrict__ w4, const float* __restrict__ b4,
    float* __restrict__ x_old, float* __restrict__ out)
{
  __shared__ uint32_t hbuf[128 * HSTRIDE];
  __shared__ uint32_t wbufA[64 * HSTRIDE];
  __shared__ uint32_t wbufB[64 * HSTRIDE];
  __shared__ float bs[320];

  int tid = threadIdx.x;
  int wave = tid >> 6, lane = tid & 63;
  int quad = lane >> 4, m16 = lane & 15;
  size_t tokBase = (size_t)blockIdx.x * 128;

  {
    size_t e = tokBase * 8 + (size_t)tid * 4;
    *(float4*)(out + e) = *(const float4*)(x + e);
  }
  if (tid < 64) {
    bs[tid]       = b0[tid];
    bs[64 + tid]  = b1[tid];
    bs[128 + tid] = b2[tid];
    bs[192 + tid] = b3[tid];
    bs[256 + tid] = b4[tid];
  }
  #pragma unroll
  for (int i = 0; i < 4; ++i) {
    int e4 = i * 256 + tid;
    int o = e4 >> 4, k = (e4 & 15) << 2;
    float4 wv = ((const float4*)w1)[e4];
    *(uint4*)(wbufA + o * HSTRIDE + k) =
        make_uint4(packpair(wv.x), packpair(wv.y), packpair(wv.z), packpair(wv.w));
  }
  __syncthreads();

  // ---- layer 0: K=8 (16 slots, quads 0..1 carry data) ----
  uint4 A0[2];
  #pragma unroll
  for (int mt = 0; mt < 2; ++mt) {
    uint4 t = make_uint4(0, 0, 0, 0);
    if (quad < 2) {
      const float* xp = x + (tokBase + wave * 32 + mt * 16 + m16) * 8 + quad * 4;
      float4 xa = *(const float4*)xp;
      t = make_uint4(packpair(xa.x), packpair(xa.y), packpair(xa.z), packpair(xa.w));
    }
    A0[mt] = t;
  }
  uint4 B0[4];
  #pragma unroll
  for (int nt = 0; nt < 4; ++nt) {
    uint4 t = make_uint4(0, 0, 0, 0);
    if (quad < 2) {
      const float* wp = w0 + (nt * 16 + m16) * 8 + quad * 4;
      float4 wa = *(const float4*)wp;
      t = make_uint4(packpair(wa.x), packpair(wa.y), packpair(wa.z), packpair(wa.w));
    }
    B0[nt] = t;
  }
  {
    f32x4 acc[2][4];
    #pragma unroll
    for (int mt = 0; mt < 2; ++mt)
      #pragma unroll
      for (int nt = 0; nt < 4; ++nt) {
        float bv = bs[nt * 16 + m16];
        acc[mt][nt] = (f32x4){bv, bv, bv, bv};
      }
    #pragma unroll
    for (int mt = 0; mt < 2; ++mt)
      #pragma unroll
      for (int nt = 0; nt < 4; ++nt)
        acc[mt][nt] = __builtin_amdgcn_mfma_f32_16x16x32_bf16(as8(A0[mt]), as8(B0[nt]), acc[mt][nt], 0, 0, 0);
    #pragma unroll
    for (int mt = 0; mt < 2; ++mt) {
      uint4 As = rot16x4(A0[mt]);
      #pragma unroll
      for (int nt = 0; nt < 4; ++nt)
        acc[mt][nt] = __builtin_amdgcn_mfma_f32_16x16x32_bf16(as8(As), as8(B0[nt]), acc[mt][nt], 0, 0, 0);
    }
    #pragma unroll
    for (int mt = 0; mt < 2; ++mt)
      #pragma unroll
      for (int nt = 0; nt < 4; ++nt)
        #pragma unroll
        for (int r = 0; r < 4; ++r) {
          float s = siluf(acc[mt][nt][r]);
          hbuf[(wave * 32 + mt * 16 + quad * 4 + r) * HSTRIDE + nt * 16 + m16] = packpair(s);
        }
  }

  const float* Ws[4] = {w1, w2, w3, w4};
  uint32_t* cur = wbufA;
  uint32_t* nxt = wbufB;
  #pragma unroll 1
  for (int lyr = 0; lyr < 4; ++lyr) {
    float4 wv[4];
    if (lyr < 3) {
      const float* wn = Ws[lyr + 1];
      #pragma unroll
      for (int i = 0; i < 4; ++i) wv[i] = ((const float4*)wn)[i * 256 + tid];
    }
    // fragment reads: raw b128, no unpack
    uint4 Bf[16];
    #pragma unroll
    for (int nt = 0; nt < 4; ++nt)
      #pragma unroll
      for (int c = 0; c < 4; ++c)
        Bf[nt * 4 + c] = *(const uint4*)(cur + (nt * 16 + m16) * HSTRIDE + c * 16 + quad * 4);
    uint4 Af[8];
    #pragma unroll
    for (int mt = 0; mt < 2; ++mt)
      #pragma unroll
      for (int c = 0; c < 4; ++c)
        Af[mt * 4 + c] = *(const uint4*)(hbuf + (wave * 32 + mt * 16 + m16) * HSTRIDE + c * 16 + quad * 4);

    f32x4 acc[2][4];
    #pragma unroll
    for (int mt = 0; mt < 2; ++mt)
      #pragma unroll
      for (int nt = 0; nt < 4; ++nt) {
        float bv = bs[(lyr + 1) * 64 + nt * 16 + m16];
        acc[mt][nt] = (f32x4){bv, bv, bv, bv};
      }
    #pragma unroll
    for (int c = 0; c < 4; ++c)
      #pragma unroll
      for (int mt = 0; mt < 2; ++mt)
        #pragma unroll
        for (int nt = 0; nt < 4; ++nt)
          acc[mt][nt] = __builtin_amdgcn_mfma_f32_16x16x32_bf16(as8(Af[mt * 4 + c]), as8(Bf[nt * 4 + c]), acc[mt][nt], 0, 0, 0);
    #pragma unroll
    for (int c = 0; c < 4; ++c)
      #pragma unroll
      for (int mt = 0; mt < 2; ++mt) {
        uint4 As = rot16x4(Af[mt * 4 + c]);
        #pragma unroll
        for (int nt = 0; nt < 4; ++nt)
          acc[mt][nt] = __builtin_amdgcn_mfma_f32_16x16x32_bf16(as8(As), as8(Bf[nt * 4 + c]), acc[mt][nt], 0, 0, 0);
      }

    if (lyr < 3) {
      #pragma unroll
      for (int i = 0; i < 4; ++i) {
        int e4 = i * 256 + tid;
        int o = e4 >> 4, k = (e4 & 15) << 2;
        *(uint4*)(nxt + o * HSTRIDE + k) =
            make_uint4(packpair(wv[i].x), packpair(wv[i].y), packpair(wv[i].z), packpair(wv[i].w));
      }
    }

    if (lyr < 3) {
      #pragma unroll
      for (int mt = 0; mt < 2; ++mt)
        #pragma unroll
        for (int nt = 0; nt < 4; ++nt)
          #pragma unroll
          for (int r = 0; r < 4; ++r) {
            float s = siluf(acc[mt][nt][r]);
            hbuf[(wave * 32 + mt * 16 + quad * 4 + r) * HSTRIDE + nt * 16 + m16] = packpair(s);
          }
    } else {
      #pragma unroll
      for (int mt = 0; mt < 2; ++mt)
        #pragma unroll
        for (int nt = 0; nt < 4; ++nt)
          #pragma unroll
          for (int r = 0; r < 4; ++r) {
            size_t t = tokBase + wave * 32 + mt * 16 + quad * 4 + r;
            x_old[t * 64 + nt * 16 + m16] = acc[mt][nt][r];
          }
    }
    __syncthreads();
    uint32_t* tmp = cur; cur = nxt; nxt = tmp;
  }
}

// ------- K2: per-batch conv + compression + v + z0 (R8 version) -------------
__global__ __launch_bounds__(256) void k_hist(
    const float* __restrict__ x_old,
    const float* __restrict__ conv_w, const float* __restrict__ conv_b,
    const float* __restrict__ comp_w, const float* __restrict__ comp_b,
    const float* __restrict__ xw0, const float* __restrict__ xb0,
    const float* __restrict__ xw1, const float* __restrict__ xb1,
    float* __restrict__ a0_o, float* __restrict__ v_o, float* __restrict__ z0_o)
{
  __shared__ float xo[LL * NN];
  __shared__ float red[32];
  __shared__ float hbuf[64];
  int b = blockIdx.x, tid = threadIdx.x;
  const float* src = x_old + (size_t)b * (LL * NN);
  #pragma unroll
  for (int i = 0; i < 6; ++i) {
    int e = (i * 256 + tid) * 4;
    *(float4*)(xo + e) = *(const float4*)(src + e);
  }
  __syncthreads();
  int c = tid & 63;
  float cw0 = conv_w[c * 3], cw1 = conv_w[c * 3 + 1], cw2 = conv_w[c * 3 + 2];
  float cb = conv_b[c];
  float acc[8];
  #pragma unroll
  for (int q = 0; q < 8; ++q) acc[q] = 0.f;
  #pragma unroll 1
  for (int j = 0; j < 24; ++j) {
    int e = j * 256 + tid;
    int t = e >> 6;
    float s = xo[t * 64 + c] * cw0 + cb;
    if (t + 2 < LL) s += xo[(t + 2) * 64 + c] * cw1;
    if (t + 4 < LL) s += xo[(t + 4) * 64 + c] * cw2;
    float hv = siluf(s);
    #pragma unroll
    for (int q = 0; q < 8; ++q) acc[q] += hv * comp_w[q * 6144 + e];
  }
  #pragma unroll
  for (int q = 0; q < 8; ++q) acc[q] = dppadd<0xB1>(acc[q]);
  #pragma unroll
  for (int q = 0; q < 8; ++q) acc[q] = dppadd<0x4E>(acc[q]);
  #pragma unroll
  for (int q = 0; q < 8; ++q) acc[q] = dppadd<0x141>(acc[q]);
  #pragma unroll
  for (int q = 0; q < 8; ++q) acc[q] = dppadd<0x128>(acc[q]);
  #pragma unroll
  for (int q = 0; q < 8; ++q) acc[q] = addswap16(acc[q]);
  #pragma unroll
  for (int q = 0; q < 8; ++q) acc[q] = addswap32(acc[q]);
  int wave = tid >> 6, lane = tid & 63;
  if (lane < 8) {
    float sel = acc[0];
    #pragma unroll
    for (int q = 1; q < 8; ++q) sel = (lane == q) ? acc[q] : sel;
    red[wave * 8 + lane] = sel;
  }
  __syncthreads();
  if (tid < 8)
    a0_o[b * 8 + tid] = red[tid] + red[8 + tid] + red[16 + tid] + red[24 + tid] + comp_b[tid];
  if (tid < 64) {
    float a2 = xb0[tid];
    #pragma unroll 8
    for (int k = 0; k < 64; ++k) a2 += xw0[tid * 64 + k] * xo[6080 + k];
    hbuf[tid] = siluf(a2);
  }
  __syncthreads();
  float vr = 0.f;
  if (tid < 64) {
    vr = xb1[tid];
    #pragma unroll 8
    for (int k = 0; k < 64; ++k) vr += xw1[tid * 64 + k] * hbuf[k];
  }
  float s2 = wave_sum(vr * vr);
  if (tid < 64) {
    float nrm = sqrtf(s2) + 1e-8f;
    v_o[b * 64 + tid] = vr / nrm;
    z0_o[b * 64 + tid] = xo[6080 + tid];
  }
}

// ------------- K3: 96-step ODE scan (R11 logic; R13: packpair output) -------
__global__ __launch_bounds__(256) void k_scan(
    const float* __restrict__ a0_i, const float* __restrict__ v_i, const float* __restrict__ z0_i,
    const float* __restrict__ nw0, const float* __restrict__ nb0_p,
    const float* __restrict__ nw1, const float* __restrict__ nb1_p,
    const float* __restrict__ lw0, const float* __restrict__ lb0_p,
    const float* __restrict__ lw1, const float* __restrict__ lb1_p,
    const float* __restrict__ spanA, float* __restrict__ atraj, uint32_t* __restrict__ ztraj)
{
  int tid = threadIdx.x;
  int lane = tid & 63;
  int wv = tid >> 6;
  int b = blockIdx.x * 4 + wv;
  float dt = fminf(fmaxf(spanA[0], 1e-8f), 7.0f);
  int i8 = lane & 7;
  bool hi32 = lane >= 32;
  // output-row label, constant on span{7,8,16}-cosets
  int rrow = ((lane ^ (lane >> 1)) & 1) | (((lane ^ (lane >> 2)) & 1) << 1) | (((lane >> 5) & 1) << 2);

  float w0r[8], wxl[4], wxp[4], g0r[8], d1r[8];
  #pragma unroll
  for (int i = 0; i < 8; ++i) w0r[i] = nw0[lane * 8 + i];
  #pragma unroll
  for (int j = 0; j < 4; ++j) wxl[j] = nw1[rrow * 64 + (lane ^ j)];
  #pragma unroll
  for (int j = 0; j < 4; ++j) wxp[j] = nw1[(rrow ^ 4) * 64 + (lane ^ j)];
  #pragma unroll
  for (int i = 0; i < 8; ++i) g0r[i] = lw0[i8 * 8 + i];
  #pragma unroll
  for (int i = 0; i < 8; ++i) d1r[i] = lw1[lane * 8 + i];
  float nb0 = nb0_p[lane];
  float nb1r = nb1_p[rrow];
  float lb0o = lb0_p[i8];
  float lb1 = lb1_p[lane];
  float v = v_i[b * 64 + lane];
  float z = z0_i[b * 64 + lane];
  float a_own = a0_i[b * 8 + rrow];
  float t0 = wave_sum(v * z);
  float w = z - 2.0f * t0 * v;
  float a_s[8];
  a_s[0] = rlane(a_own, 0);  a_s[1] = rlane(a_own, 2);
  a_s[2] = rlane(a_own, 4);  a_s[3] = rlane(a_own, 6);
  a_s[4] = rlane(a_own, 32); a_s[5] = rlane(a_own, 34);
  a_s[6] = rlane(a_own, 36); a_s[7] = rlane(a_own, 38);

  float* ab = atraj + (size_t)b * (PP * 8);
  uint32_t* zb = ztraj + (size_t)b * (PP * NN);
  bool astore = (lane & 0x19) == 0;   // lanes {0,2,4,6,32,34,36,38}

  auto step_rec = [&]() {
    // h = silu(nb0 + W0 a)
    float u0 = w0r[0] * a_s[0] + w0r[1] * a_s[1];
    float u1 = w0r[2] * a_s[2] + w0r[3] * a_s[3];
    float u2 = w0r[4] * a_s[4] + w0r[5] * a_s[5];
    float u3 = w0r[6] * a_s[6] + w0r[7] * a_s[7];
    float h = siluf(nb0 + ((u0 + u1) + (u2 + u3)));
    // gather over M = {0,1,2,3,32,33,34,35}: DPP + one permlane32
    float hv1 = dppmov<0xB1>(h);
    float hv2 = dppmov<0x4E>(h);
    float hv3 = dppmov<0x1B>(h);
    float slo = (wxl[0] * h + wxl[1] * hv1) + (wxl[2] * hv2 + wxl[3] * hv3);
    float pre = (wxp[0] * h + wxp[1] * hv1) + (wxp[2] * hv2 + wxp[3] * hv3);
    float ps = slo + movswap32(pre, hi32);
    // reduce over S = span{7,8,16}: all VALU
    ps = dppadd<0x141>(ps);
    ps = dppadd<0x128>(ps);
    ps = addswap16(ps);
    float da = tanhf_fast(ps + nb1r);
    // d chain (independent; i8-labeled as before)
    float e0 = g0r[0] * a_s[0] + g0r[1] * a_s[1];
    float e1 = g0r[2] * a_s[2] + g0r[3] * a_s[3];
    float e2 = g0r[4] * a_s[4] + g0r[5] * a_s[5];
    float e3 = g0r[6] * a_s[6] + g0r[7] * a_s[7];
    float g_own = siluf(lb0o + ((e0 + e1) + (e2 + e3)));
    float f0 = d1r[0] * rlane(g_own, 0) + d1r[1] * rlane(g_own, 1);
    float f1 = d1r[2] * rlane(g_own, 2) + d1r[3] * rlane(g_own, 3);
    float f2 = d1r[4] * rlane(g_own, 4) + d1r[5] * rlane(g_own, 5);
    float f3 = d1r[6] * rlane(g_own, 6) + d1r[7] * rlane(g_own, 7);
    float d = lb1 + ((f0 + f1) + (f2 + f3));
    // state update
    a_own += dt * da;
    a_s[0] = rlane(a_own, 0);  a_s[1] = rlane(a_own, 2);
    a_s[2] = rlane(a_own, 4);  a_s[3] = rlane(a_own, 6);
    a_s[4] = rlane(a_own, 32); a_s[5] = rlane(a_own, 34);
    a_s[6] = rlane(a_own, 36); a_s[7] = rlane(a_own, 38);
    w *= (1.0f + dt * d);
  };

  step_rec();                 // step 0
  float wo = w, ao = a_own;
  #pragma unroll 1
  for (int p = 1; p < PP; ++p) {
    float woc = wo, aoc = ao;
    step_rec();               // recurrence for step p (chain)
    wo = w; ao = a_own;
    // output row p-1 (independent of the recurrence above)
    float t1 = wave_sum(v * woc);
    float zv = woc - 2.0f * t1 * v;
    if (astore) ab[(p - 1) * 8 + rrow] = aoc;
    zb[(p - 1) * 64 + lane] = packpair(zv);
  }
  {
    float t1 = wave_sum(v * wo);
    float zv = wo - 2.0f * t1 * v;
    if (astore) ab[(PP - 1) * 8 + rrow] = ao;
    zb[(PP - 1) * 64 + lane] = packpair(zv);
  }
}

// --------- K4: post nets (R13: interleaved-pair everywhere, no unpack) ------
// R12 PMC on k_post: MfmaUtil 8.6%, VALUBusy 46.5% -> same readfrag unpack
// tax k_xproj had (~480 VALU ops/block). R13: ztraj is now packpair (from
// k_scan), wbuf/ebuf staged as packpair -> A-frags are raw dwordx4 global
// loads, B/E-frags raw ds_read_b128; straight MFMA + rot16(A) MFMA = exact
// 4-term product. MFMA 60 -> 80 per block, VALU -~480 ops.
__global__ __launch_bounds__(256, 4) void k_post(
    const float* __restrict__ atraj, const uint32_t* __restrict__ ztraj,
    const float* __restrict__ cw0, const float* __restrict__ cb0,
    const float* __restrict__ cw1, const float* __restrict__ cb1,
    const float* __restrict__ zw0, const float* __restrict__ zb0,
    const float* __restrict__ zw1, const float* __restrict__ zb1,
    float* __restrict__ out)
{
  __shared__ uint32_t wbuf[144 * HSTRIDE];  // 39168 B; rows 0..63 reused as ebuf
  __shared__ float    cw0s[64];
  __shared__ float    cb0s[8];
  __shared__ float    zb0s[64];
  __shared__ float    zb1s[8];

  int tid = threadIdx.x;
  int wave = tid >> 6, lane = tid & 63;
  int quad = lane >> 4, m16 = lane & 15;
  size_t tokBase = (size_t)blockIdx.x * 64;

  // ---- stage all weights once (144 rows x 64), interleaved-pair ----
  #pragma unroll
  for (int i = 0; i < 36; ++i) {
    int e = i * 256 + tid;
    int o = e >> 6, k = e & 63;
    float wv;
    if (o < 64)       wv = cw1[(((o >> 3) * 64 + k) << 3) + (o & 7)];
    else if (o < 72)  wv = cb1[(o - 64) * 64 + k];
    else if (o < 136) wv = zw0[(o - 72) * 64 + k];
    else              wv = zw1[(o - 136) * 64 + k];
    wbuf[o * HSTRIDE + k] = packpair(wv);
  }
  if (tid < 64) cw0s[tid] = cw0[tid];
  if (tid < 8)  cb0s[tid] = cb0[tid];
  if (tid < 64) zb0s[tid] = zb0[tid];
  if (tid < 8)  zb1s[tid] = zb1[tid];
  __syncthreads();

  // ---- A-frags (Z) raw from global packed (packpair) ztraj ----
  const uint32_t* zp = ztraj + (tokBase + wave * 16 + m16) * 64;
  uint4 Az[4], Azr[4];
  #pragma unroll
  for (int c = 0; c < 4; ++c) {
    Az[c]  = *(const uint4*)(zp + c * 16 + quad * 4);
    Azr[c] = rot16x4(Az[c]);
  }

  // ---- pass 1: M (nt 0..3) + ybias (nt 4) -> registers ----
  f32x4 acc1[5];
  #pragma unroll
  for (int nt = 0; nt < 5; ++nt) {
    f32x4 acc = (f32x4){0.f, 0.f, 0.f, 0.f};
    #pragma unroll
    for (int c = 0; c < 4; ++c) {
      uint4 Bf = *(const uint4*)(wbuf + (nt * 16 + m16) * HSTRIDE + c * 16 + quad * 4);
      acc = __builtin_amdgcn_mfma_f32_16x16x32_bf16(as8(Az[c]),  as8(Bf), acc, 0, 0, 0);
      acc = __builtin_amdgcn_mfma_f32_16x16x32_bf16(as8(Azr[c]), as8(Bf), acc, 0, 0, 0);
    }
    acc1[nt] = acc;
  }
  __syncthreads();  // all pass-1 reads of rows 0..79 done -> rows 0..63 reusable

  // ---- pass 2: E = silu(Z @ zw0^T + zb0) -> ebuf (= wbuf rows 0..63) ----
  uint32_t* ebuf = wbuf;
  #pragma unroll
  for (int nt = 0; nt < 4; ++nt) {
    f32x4 acc = (f32x4){0.f, 0.f, 0.f, 0.f};
    #pragma unroll
    for (int c = 0; c < 4; ++c) {
      uint4 Bf = *(const uint4*)(wbuf + (72 + nt * 16 + m16) * HSTRIDE + c * 16 + quad * 4);
      acc = __builtin_amdgcn_mfma_f32_16x16x32_bf16(as8(Az[c]),  as8(Bf), acc, 0, 0, 0);
      acc = __builtin_amdgcn_mfma_f32_16x16x32_bf16(as8(Azr[c]), as8(Bf), acc, 0, 0, 0);
    }
    int m = nt * 16 + m16;
    float zbv = zb0s[m];
    #pragma unroll
    for (int r = 0; r < 4; ++r) {
      float e = siluf(acc[r] + zbv);
      ebuf[(wave * 16 + quad * 4 + r) * HSTRIDE + m] = packpair(e);
    }
  }

  // ---- pass 3: add = E @ zw1^T + zb1 (ebuf rows wave-private, in-order) ----
  f32x4 acc3;
  {
    f32x4 acc = (f32x4){0.f, 0.f, 0.f, 0.f};
    int brow = 136 + (m16 & 7);   // duplicate rows for m16>=8; results unused there
    #pragma unroll
    for (int c = 0; c < 4; ++c) {
      uint4 Ez = *(const uint4*)(ebuf + (wave * 16 + m16) * HSTRIDE + c * 16 + quad * 4);
      uint4 Bf = *(const uint4*)(wbuf + brow * HSTRIDE + c * 16 + quad * 4);
      acc = __builtin_amdgcn_mfma_f32_16x16x32_bf16(as8(Ez),         as8(Bf), acc, 0, 0, 0);
      acc = __builtin_amdgcn_mfma_f32_16x16x32_bf16(as8(rot16x4(Ez)), as8(Bf), acc, 0, 0, 0);
    }
    acc3 = acc;
  }

  // ---- in-register combine ----
  int j = m16 & 7;
  float cwj[8];
  #pragma unroll
  for (int i = 0; i < 8; ++i) cwj[i] = cw0s[j * 8 + i];
  float cbj = cb0s[j];
  #pragma unroll
  for (int r = 0; r < 4; ++r) {
    size_t idx = tokBase + wave * 16 + quad * 4 + r;
    const float* ap = atraj + idx * 8;
    float4 a0v = *(const float4*)ap;
    float4 a1v = *(const float4*)(ap + 4);
    float g2v = cbj
      + cwj[0] * a0v.x + cwj[1] * a0v.y + cwj[2] * a0v.z + cwj[3] * a0v.w
      + cwj[4] * a1v.x + cwj[5] * a1v.y + cwj[6] * a1v.z + cwj[7] * a1v.w;
    g2v = siluf(g2v);
    float yc[4], qo[4];
    #pragma unroll
    for (int nt = 0; nt < 4; ++nt) {
      float p = acc1[nt][r] * g2v;
      p = dppadd<0xB1>(p);
      p = dppadd<0x4E>(p);
      p = dppadd<0x141>(p);     // sum over 8-lane half-row
      yc[nt] = p;               // c = nt*2 + (m16>>3)
      qo[nt] = dppmov<0x128>(p);// partner half's value: c = nt*2 + 1-(m16>>3)
    }
    if (m16 < 8) {
      int cc = m16;
      int nt = cc >> 1;
      float ye = (nt == 0) ? yc[0] : (nt == 1) ? yc[1] : (nt == 2) ? yc[2] : yc[3];
      float yo = (nt == 0) ? qo[0] : (nt == 1) ? qo[1] : (nt == 2) ? qo[2] : qo[3];
      float y = (cc & 1) ? yo : ye;
      y += acc1[4][r] + acc3[r] + zb1s[cc];
      out[(size_t)(BB * LL * 8) + idx * 8 + cc] = y;
    }
  }
}

extern "C" void kernel_launch(void* const* d_in, const int* in_sizes, int n_in,
                              void* d_out, int out_size, void* d_ws, size_t ws_size,
                              hipStream_t stream) {
  const float* x      = (const float*)d_in[0];
  const float* xp_w0  = (const float*)d_in[1];
  const float* xp_b0  = (const float*)d_in[2];
  const float* xp_w1  = (const float*)d_in[3];
  const float* xp_b1  = (const float*)d_in[4];
  const float* xp_w2  = (const float*)d_in[5];
  const float* xp_b2  = (const float*)d_in[6];
  const float* xp_w3  = (const float*)d_in[7];
  const float* xp_b3  = (const float*)d_in[8];
  const float* xp_w4  = (const float*)d_in[9];
  const float* xp_b4  = (const float*)d_in[10];
  const float* xpp_w0 = (const float*)d_in[11];
  const float* xpp_b0 = (const float*)d_in[12];
  const float* xpp_w1 = (const float*)d_in[13];
  const float* xpp_b1 = (const float*)d_in[14];
  const float* conv_w = (const float*)d_in[15];
  const float* conv_b = (const float*)d_in[16];
  const float* span_A = (const float*)d_in[17];
  const float* comp_w = (const float*)d_in[18];
  const float* comp_b = (const float*)d_in[19];
  const float* net_w0 = (const float*)d_in[20];
  const float* net_b0 = (const float*)d_in[21];
  const float* net_w1 = (const float*)d_in[22];
  const float* net_b1 = (const float*)d_in[23];
  const float* lo_w0  = (const float*)d_in[24];
  const float* lo_b0  = (const float*)d_in[25];
  const float* lo_w1  = (const float*)d_in[26];
  const float* lo_b1  = (const float*)d_in[27];
  const float* lc_w0  = (const float*)d_in[28];
  const float* lc_b0  = (const float*)d_in[29];
  const float* lc_w1  = (const float*)d_in[30];
  const float* lc_b1  = (const float*)d_in[31];
  const float* lz_w0  = (const float*)d_in[32];
  const float* lz_b0  = (const float*)d_in[33];
  const float* lz_w1  = (const float*)d_in[34];
  const float* lz_b1  = (const float*)d_in[35];

  float*    ws    = (float*)d_ws;
  float*    x_old = ws;                    // (B,L,64) fp32
  uint32_t* ztraj = (uint32_t*)ws;         // (B,P,64) packed u32 — aliases x_old
  float*    atraj = ws + 12582912;         // (B,P,8)
  float*    a0    = ws + 14155776;         // (B,8)
  float*    vv    = a0 + 2048 * 8;         // (B,64)
  float*    z0    = vv + 2048 * 64;        // (B,64)
  float*    out   = (float*)d_out;

  hipLaunchKernelGGL(k_xproj, dim3(1536), dim3(256), 0, stream,
                     x, xp_w0, xp_b0, xp_w1, xp_b1, xp_w2, xp_b2, xp_w3, xp_b3,
                     xp_w4, xp_b4, x_old, out);
  hipLaunchKernelGGL(k_hist, dim3(2048), dim3(256), 0, stream,
                     x_old, conv_w, conv_b, comp_w, comp_b,
                     xpp_w0, xpp_b0, xpp_w1, xpp_b1, a0, vv, z0);
  hipLaunchKernelGGL(k_scan, dim3(512), dim3(256), 0, stream,
                     a0, vv, z0, net_w0, net_b0, net_w1, net_b1,
                     lo_w0, lo_b0, lo_w1, lo_b1, span_A, atraj, ztraj);
  hipLaunchKernelGGL(k_post, dim3(3072), dim3(256), 0, stream,
                     atraj, ztraj, lc_w0, lc_b0, lc_w1, lc_b1,
                     lz_w0, lz_b0, lz_w1, lz_b1, out);
}